// Round 6
// baseline (431.440 us; speedup 1.0000x reference)
//
#include <hip/hip_runtime.h>
#include <math.h>

// Problem constants (B=64, N=512, F_IN=D=128, K=32, INTER=256)
#define M_ROWS 32768
#define NNODES 512
#define KNBR   32
#define EPSBN  1e-5f

typedef __bf16 bf16x8 __attribute__((ext_vector_type(8)));
typedef __bf16 bf16x4 __attribute__((ext_vector_type(4)));
typedef __bf16 bf16x2 __attribute__((ext_vector_type(2)));
typedef float  f32x4  __attribute__((ext_vector_type(4)));

#if defined(__has_builtin)
#if __has_builtin(__builtin_amdgcn_global_load_lds)
#define HAVE_GLL 1
#endif
#endif

// async global->LDS 16B: LDS dst must be wave-uniform base + lane*16
__device__ __forceinline__ void async_ld16(void* lds, const void* g){
#ifdef HAVE_GLL
    __builtin_amdgcn_global_load_lds((__attribute__((address_space(1))) void*)(g),
                                     (__attribute__((address_space(3))) void*)(lds),
                                     16, 0, 0);
#else
    *(bf16x8*)lds = *(const bf16x8*)g;
#endif
}

// ---------------------------------------------------------------------------
// K1: blocks 0..511    -> xlin GEMM tile (64 rows) + raw score epilogue
//     blocks 512..1023 -> topk row (bid-512) [wave0]
//     blocks 1024..1071-> pack W1/W2 to bf16 frag order
//     block  1072      -> zero BN stats
// ---------------------------------------------------------------------------
__global__ __launch_bounds__(256) void k1_kernel(
    const float* __restrict__ data, const float* __restrict__ emb,
    const float* __restrict__ lin_W, const float* __restrict__ W1,
    const float* __restrict__ W2,
    const float* __restrict__ att_i, const float* __restrict__ att_j,
    int* __restrict__ topk,
    __bf16* __restrict__ Wp1, __bf16* __restrict__ Wp2,
    float* __restrict__ stats,
    __bf16* __restrict__ xlin, float* __restrict__ s_i, float* __restrict__ s_j)
{
    __shared__ __align__(16) char sm[50176];   // union: xlin tiles / topk bufs
    int bid = blockIdx.x, tid = threadIdx.x;

    if (bid < 512){
        // ================= xlin GEMM tile =================
        __bf16 (*As)[136] = (__bf16(*)[136])sm;          // 64 x 136
        bf16x8* Bp = (bf16x8*)(sm + 17408);              // 2048 granules
        int lane = tid & 63, wv = tid >> 6;
        int mrow = lane & 15, q = lane >> 4;
        int row0 = bid * 64;

        // self-pack lin_W: Bp[g][j] = lin_W[((g>>7)*8 + j)*128 + (g&127)]
        #pragma unroll
        for (int i = 0; i < 8; ++i){
            int g = tid + i*256;
            int kg = g >> 7, c = g & 127;
            bf16x8 pk;
            #pragma unroll
            for (int j = 0; j < 8; ++j) pk[j] = (__bf16)lin_W[(size_t)(kg*8 + j)*128 + c];
            Bp[g] = pk;
        }
        // stage A fp32 -> bf16
        #pragma unroll
        for (int i = 0; i < 4; ++i){
            int p = tid + i*256;
            int r = p >> 4, c8 = p & 15;
            const float* src = &data[(size_t)(row0 + r)*128 + c8*8];
            float4 a0 = *(const float4*)src;
            float4 a1 = *(const float4*)(src + 4);
            bf16x8 o;
            o[0]=(__bf16)a0.x; o[1]=(__bf16)a0.y; o[2]=(__bf16)a0.z; o[3]=(__bf16)a0.w;
            o[4]=(__bf16)a1.x; o[5]=(__bf16)a1.y; o[6]=(__bf16)a1.z; o[7]=(__bf16)a1.w;
            *(bf16x8*)&As[r][c8*8] = o;
        }
        __syncthreads();

        f32x4 acc[8];
        #pragma unroll
        for (int ct = 0; ct < 8; ++ct) acc[ct] = (f32x4){0.f,0.f,0.f,0.f};
        #pragma unroll
        for (int ks = 0; ks < 4; ++ks){
            bf16x8 a = *(const bf16x8*)&As[wv*16 + mrow][ks*32 + q*8];
            #pragma unroll
            for (int ct = 0; ct < 8; ++ct){
                bf16x8 bb = Bp[(ks*4 + q)*128 + ct*16 + mrow];
                acc[ct] = __builtin_amdgcn_mfma_f32_16x16x32_bf16(a, bb, acc[ct], 0, 0, 0);
            }
        }

        // epilogue: store bf16 + raw attention scores (e_i/e_j added in agg)
        float ai[4] = {0,0,0,0}, aj[4] = {0,0,0,0};
        #pragma unroll
        for (int ct = 0; ct < 8; ++ct){
            int col = ct*16 + mrow;
            float wti = att_i[col], wtj = att_j[col];
            #pragma unroll
            for (int reg = 0; reg < 4; ++reg){
                int row = row0 + wv*16 + q*4 + reg;
                float v = acc[ct][reg];
                xlin[(size_t)row*128 + col] = (__bf16)v;
                ai[reg] += v*wti; aj[reg] += v*wtj;
            }
        }
        #pragma unroll
        for (int mask = 1; mask < 16; mask <<= 1){
            #pragma unroll
            for (int reg = 0; reg < 4; ++reg){
                ai[reg] += __shfl_xor(ai[reg], mask);
                aj[reg] += __shfl_xor(aj[reg], mask);
            }
        }
        if (mrow == 0){
            #pragma unroll
            for (int reg = 0; reg < 4; ++reg){
                int row = row0 + wv*16 + q*4 + reg;
                s_i[row] = ai[reg];
                s_j[row] = aj[reg];
            }
        }
        return;
    }

    if (bid >= 1024){
        if (bid == 1072){
            for (int i = tid; i < 1536; i += 256) stats[i] = 0.f;
            return;
        }
        // pack W1 (4096 granules) then W2 (8192 granules)
        int gidx = (bid - 1024)*256 + tid;            // 0..12287
        const float* W; __bf16* o; int lg;
        if (gidx < 4096){ W = W1; o = Wp1; lg = gidx; }
        else            { W = W2; o = Wp2; lg = gidx - 4096; }
        int kg = lg >> 8, c = lg & 255;
        bf16x8 pk;
        #pragma unroll
        for (int j = 0; j < 8; ++j) pk[j] = (__bf16)W[(size_t)(kg*8 + j)*256 + c];
        *(bf16x8*)&o[(size_t)lg*8] = pk;
        return;
    }

    // ================= topk for row i =================
    float* wi   = (float*)sm;           // 128
    float* cosv = (float*)(sm + 512);   // 512
    int i = bid - 512;
    if (tid < 128) wi[tid] = emb[i*128 + tid];
    __syncthreads();
    float ni = 0.f;
    #pragma unroll 8
    for (int d = 0; d < 128; ++d) ni += wi[d]*wi[d];
    float rni = sqrtf(ni);
    for (int jj = tid; jj < 512; jj += 256){
        const float4* wj4 = (const float4*)(emb + jj*128);
        float dot = 0.f, nj = 0.f;
        #pragma unroll 8
        for (int d4 = 0; d4 < 32; ++d4){
            float4 w = wj4[d4];
            dot += wi[4*d4+0]*w.x + wi[4*d4+1]*w.y + wi[4*d4+2]*w.z + wi[4*d4+3]*w.w;
            nj  += w.x*w.x + w.y*w.y + w.z*w.z + w.w*w.w;
        }
        cosv[jj] = dot / (rni * sqrtf(nj));
    }
    __syncthreads();
    if (tid < 64){
        int lane = tid;
        float v[8];
        #pragma unroll
        for (int jj = 0; jj < 8; ++jj) v[jj] = cosv[lane + 64*jj];
        for (int k = 0; k < KNBR; ++k){
            float bv = v[0]; int bj = 0;
            #pragma unroll
            for (int jj = 1; jj < 8; ++jj) if (v[jj] > bv){ bv = v[jj]; bj = jj; }
            int bi = lane + 64*bj;
            #pragma unroll
            for (int mask = 1; mask < 64; mask <<= 1){
                float ov = __shfl_xor(bv, mask);
                int   oi = __shfl_xor(bi, mask);
                if (ov > bv || (ov == bv && oi < bi)){ bv = ov; bi = oi; }
            }
            if (lane == 0) topk[i*KNBR + k] = bi;
            if ((bi & 63) == lane){
                int jj = bi >> 6;
                #pragma unroll
                for (int j2 = 0; j2 < 8; ++j2) if (j2 == jj) v[j2] = -2e30f;
            }
        }
    }
}

// ---------------------------------------------------------------------------
// agg v3: ONE WAVE per node (8192 blocks x 4 waves), XCD-locality swizzle so
// each XCD's blocks gather from only 8 batch slices (L2-resident), shuffle
// softmax, bf16 gathers, fused gnn column stats (LDS + atomics).
// ---------------------------------------------------------------------------
__global__ __launch_bounds__(256) void agg_kernel(const __bf16* __restrict__ xl,
                                                  const float* __restrict__ s_i,
                                                  const float* __restrict__ s_j,
                                                  const float* __restrict__ e_i,
                                                  const float* __restrict__ e_j,
                                                  const int* __restrict__ topk,
                                                  const float2* __restrict__ gnn_bias2,
                                                  __bf16* __restrict__ aggp,
                                                  float* __restrict__ gnnstats){
    int tid = threadIdx.x;
    int wv = tid >> 6, lane = tid & 63;
    // XCD swizzle: blk%8 ~ XCD; give each XCD 8 whole batches.
    int blk = blockIdx.x;                        // 0..8191
    int xcd = blk & 7, grp = blk >> 3;           // grp 0..1023
    int batch = xcd*8 + (grp >> 7);              // 0..63
    int node  = (grp & 127)*4 + wv;              // 0..511
    int m = batch*512 + node;
    int i = node;

    int src; bool valid;
    if (lane < KNBR){ int j = topk[i*KNBR + lane]; src = batch*512 + j; valid = (j != i); }
    else            { src = m; valid = (lane == KNBR); }
    float l = s_i[m] + e_i[i] + s_j[src] + e_j[src & 511];
    l = (l >= 0.f) ? l : 0.2f*l;                 // leaky_relu 0.2
    l = valid ? l : -1e30f;
    float mx = l;
    #pragma unroll
    for (int mask = 1; mask < 64; mask <<= 1) mx = fmaxf(mx, __shfl_xor(mx, mask));
    float e = valid ? __expf(l - mx) : 0.f;
    float den = e;
    #pragma unroll
    for (int mask = 1; mask < 64; mask <<= 1) den += __shfl_xor(den, mask);
    float alpha = e / den;

    float2 acc = make_float2(0.f, 0.f);
    #pragma unroll 4
    for (int k = 0; k < 33; ++k){
        float a = __shfl(alpha, k);
        int   s = __shfl(src, k);
        bf16x2 v = *(const bf16x2*)&xl[(size_t)s*128 + lane*2];
        acc.x += a*(float)v[0]; acc.y += a*(float)v[1];
    }
    float2 bv = gnn_bias2[lane];
    bf16x2 o;
    o[0] = (__bf16)(acc.x + bv.x);
    o[1] = (__bf16)(acc.y + bv.y);
    *(bf16x2*)&aggp[(size_t)m*128 + lane*2] = o;

    // fused gnn column stats (on rounded values)
    float r0 = (float)o[0], r1 = (float)o[1];
    __shared__ float rS[4][128], rQ[4][128];
    rS[wv][lane*2]   = r0; rS[wv][lane*2+1] = r1;
    rQ[wv][lane*2]   = r0*r0; rQ[wv][lane*2+1] = r1*r1;
    __syncthreads();
    if (tid < 128){
        float ts = rS[0][tid] + rS[1][tid] + rS[2][tid] + rS[3][tid];
        float tq = rQ[0][tid] + rQ[1][tid] + rQ[2][tid] + rQ[3][tid];
        atomicAdd(&gnnstats[tid],       ts);
        atomicAdd(&gnnstats[128 + tid], tq);
    }
}

// ---------------------------------------------------------------------------
// e_i[n], e_j[n] for all 512 nodes (tiny)
// ---------------------------------------------------------------------------
__global__ __launch_bounds__(256) void escore_kernel(const float* __restrict__ emb,
                                                     const float* __restrict__ aem_i,
                                                     const float* __restrict__ aem_j,
                                                     float* __restrict__ e_i,
                                                     float* __restrict__ e_j){
    int tid = threadIdx.x;
    int wid = tid >> 6, lane = tid & 63;         // 4 waves
    for (int n = blockIdx.x*4 + wid; n < NNODES; n += gridDim.x*4){
        const float* w = emb + (size_t)n*128;
        float ai = w[lane]*aem_i[lane] + w[lane+64]*aem_i[lane+64];
        float aj = w[lane]*aem_j[lane] + w[lane+64]*aem_j[lane+64];
        #pragma unroll
        for (int off = 32; off; off >>= 1){
            ai += __shfl_down(ai, off);
            aj += __shfl_down(aj, off);
        }
        if (lane == 0){ e_i[n] = ai; e_j[n] = aj; }
    }
}

// ---------------------------------------------------------------------------
// bf16 MFMA GEMM (128x128 tile, 2x2 wave grid).
// GATE: A-staging = relu(bn_out( relu(bn_gnn(agg)) * emb )), K=128
// else: A-staging = relu(bn1(t1)), K=256
// ---------------------------------------------------------------------------
template<bool GATE>
__global__ __launch_bounds__(256) void gemm2_kernel(
    const __bf16* __restrict__ A, int a_stride, int Ktot,
    const float* __restrict__ st1, const float* __restrict__ g1, const float* __restrict__ b1,
    const float* __restrict__ emb,
    const float* __restrict__ st2, const float* __restrict__ g2, const float* __restrict__ b2,
    const __bf16* __restrict__ Wp, int Ctot,
    const float* __restrict__ bias,
    __bf16* __restrict__ outp,
    float* __restrict__ outstats, int outK)
{
    __shared__ __align__(16) __bf16 As[128][136];
    __shared__ __align__(16) __bf16 Bp[16][128][8];
    __shared__ float nsc1[128], nsh1[128], nsc2[128], nsh2[128];
    __shared__ float statS[128], statQ[128];

    int tid  = threadIdx.x;
    int lane = tid & 63, wv = tid >> 6;
    int mrow = lane & 15, q = lane >> 4;
    int wvr = wv & 1, wvc = wv >> 1;             // 2x2 wave grid
    int cb0  = blockIdx.y * 128;
    int row0 = blockIdx.x * 128;

    f32x4 acc[4][4];
    #pragma unroll
    for (int rt = 0; rt < 4; ++rt)
        #pragma unroll
        for (int ct = 0; ct < 4; ++ct)
            acc[rt][ct] = (f32x4){0.f,0.f,0.f,0.f};

    for (int kc = 0; kc < Ktot; kc += 128){
        if (tid < 128){
            int f = kc + tid;
            float mean = st1[f] * (1.f/32768.f);
            float var  = st1[Ktot + f] * (1.f/32768.f) - mean*mean;
            float sc   = g1[f] / sqrtf(var + EPSBN);
            nsc1[tid] = sc;
            nsh1[tid] = b1[f] - mean*sc;
            if (GATE){
                float mean2 = st2[tid] * (1.f/32768.f);
                float var2  = st2[128 + tid] * (1.f/32768.f) - mean2*mean2;
                float sc2   = g2[tid] / sqrtf(var2 + EPSBN);
                nsc2[tid] = sc2;
                nsh2[tid] = b2[tid] - mean2*sc2;
            }
        }
        __syncthreads();

        // B: async 16B granules into LDS (pre-packed frag order)
        int kg0 = kc >> 3;
        #pragma unroll
        for (int i = 0; i < 8; ++i){
            int p = tid + i*256;
            const __bf16* src = Wp + ((size_t)(kg0 + (p>>7))*Ctot + cb0 + (p&127))*8;
            async_ld16((__bf16*)Bp + (size_t)p*8, src);
        }
        // A: through regs with fused activation chain
        #pragma unroll
        for (int i = 0; i < 8; ++i){
            int p = tid + i*256;
            int r = p >> 4, c8 = p & 15;
            bf16x8 v = *(const bf16x8*)&A[(size_t)(row0 + r)*a_stride + kc + c8*8];
            bf16x8 o;
            if (GATE){
                const float* ep = &emb[(size_t)((row0 + r) & 511)*128 + c8*8];
                float4 e0 = *(const float4*)ep;
                float4 e1 = *(const float4*)(ep + 4);
                float ee[8] = {e0.x,e0.y,e0.z,e0.w,e1.x,e1.y,e1.z,e1.w};
                #pragma unroll
                for (int j = 0; j < 8; ++j){
                    int f = c8*8 + j;
                    float hv = fmaxf((float)v[j]*nsc1[f] + nsh1[f], 0.f) * ee[j];
                    o[j] = (__bf16)fmaxf(hv*nsc2[f] + nsh2[f], 0.f);
                }
            } else {
                #pragma unroll
                for (int j = 0; j < 8; ++j){
                    int f = c8*8 + j;
                    o[j] = (__bf16)fmaxf((float)v[j]*nsc1[f] + nsh1[f], 0.f);
                }
            }
            *(bf16x8*)&As[r][c8*8] = o;
        }
        __syncthreads();

        #pragma unroll
        for (int ks = 0; ks < 4; ++ks){
            bf16x8 a[4];
            #pragma unroll
            for (int rt = 0; rt < 4; ++rt)
                a[rt] = *(const bf16x8*)&As[wvr*64 + rt*16 + mrow][ks*32 + q*8];
            #pragma unroll
            for (int ct = 0; ct < 4; ++ct){
                bf16x8 bb = *(const bf16x8*)&Bp[ks*4 + q][wvc*64 + ct*16 + mrow][0];
                #pragma unroll
                for (int rt = 0; rt < 4; ++rt)
                    acc[rt][ct] = __builtin_amdgcn_mfma_f32_16x16x32_bf16(a[rt], bb, acc[rt][ct], 0, 0, 0);
            }
        }
        __syncthreads();
    }

    if (tid < 128){ statS[tid] = 0.f; statQ[tid] = 0.f; }
    __syncthreads();

    float cs[4] = {0,0,0,0}, cq[4] = {0,0,0,0};
    #pragma unroll
    for (int ct = 0; ct < 4; ++ct){
        int lcol = wvc*64 + ct*16 + mrow;
        int col  = cb0 + lcol;
        float bvv = bias[col];
        #pragma unroll
        for (int rt = 0; rt < 4; ++rt){
            #pragma unroll
            for (int reg = 0; reg < 4; ++reg){
                int row = row0 + wvr*64 + rt*16 + q*4 + reg;
                __bf16 ov = (__bf16)(acc[rt][ct][reg] + bvv);
                outp[(size_t)row*Ctot + col] = ov;
                float fv = (float)ov; cs[ct] += fv; cq[ct] += fv*fv;
            }
        }
    }
    #pragma unroll
    for (int ct = 0; ct < 4; ++ct){
        float s  = cs[ct]; s  += __shfl_xor(s, 16);  s  += __shfl_xor(s, 32);
        float qq = cq[ct]; qq += __shfl_xor(qq, 16); qq += __shfl_xor(qq, 32);
        if (q == 0){
            atomicAdd(&statS[wvc*64 + ct*16 + mrow], s);
            atomicAdd(&statQ[wvc*64 + ct*16 + mrow], qq);
        }
    }
    __syncthreads();
    if (tid < 128){
        atomicAdd(&outstats[cb0 + tid],        statS[tid]);
        atomicAdd(&outstats[outK + cb0 + tid], statQ[tid]);
    }
}

// ---------------------------------------------------------------------------
// hstats: h = relu(bn_gnn(agg))*emb computed on the fly (NOT stored);
// accumulate column sum/sumsq of h into hstats.
// ---------------------------------------------------------------------------
__global__ __launch_bounds__(256) void hstats_kernel(const __bf16* __restrict__ agg,
                                                     const float* __restrict__ gst,
                                                     const float* __restrict__ g,
                                                     const float* __restrict__ bta,
                                                     const float* __restrict__ emb,
                                                     float* __restrict__ hstats){
    int tid = threadIdx.x;
    int cg = tid & 31, rs = tid >> 5;
    int c0 = cg*4;
    float sc[4], sh[4];
    #pragma unroll
    for (int j = 0; j < 4; ++j){
        float mean = gst[c0+j] * (1.f/32768.f);
        float var  = gst[128 + c0+j] * (1.f/32768.f) - mean*mean;
        sc[j] = g[c0+j] / sqrtf(var + EPSBN);
        sh[j] = bta[c0+j] - mean*sc[j];
    }
    float s[4] = {0,0,0,0}, qq[4] = {0,0,0,0};
    for (int m = blockIdx.x*8 + rs; m < M_ROWS; m += gridDim.x*8){
        bf16x4 v = *(const bf16x4*)&agg[(size_t)m*128 + c0];
        float4 e = *(const float4*)&emb[(size_t)(m & 511)*128 + c0];
        float f0 = fmaxf((float)v[0]*sc[0] + sh[0], 0.f) * e.x;
        float f1 = fmaxf((float)v[1]*sc[1] + sh[1], 0.f) * e.y;
        float f2 = fmaxf((float)v[2]*sc[2] + sh[2], 0.f) * e.z;
        float f3 = fmaxf((float)v[3]*sc[3] + sh[3], 0.f) * e.w;
        s[0]+=f0; qq[0]+=f0*f0; s[1]+=f1; qq[1]+=f1*f1;
        s[2]+=f2; qq[2]+=f2*f2; s[3]+=f3; qq[3]+=f3*f3;
    }
    __shared__ float rS[8][128], rQ[8][128];
    #pragma unroll
    for (int j = 0; j < 4; ++j){ rS[rs][c0+j] = s[j]; rQ[rs][c0+j] = qq[j]; }
    __syncthreads();
    if (tid < 128){
        float ts = 0.f, tq = 0.f;
        #pragma unroll
        for (int u = 0; u < 8; ++u){ ts += rS[u][tid]; tq += rQ[u][tid]; }
        atomicAdd(&hstats[tid],       ts);
        atomicAdd(&hstats[128 + tid], tq);
    }
}

// ---------------------------------------------------------------------------
// out[m] = relu(bn2(t2[m,:])) . W3 + b3   (one wave per row, bf16 in, f32 out)
// ---------------------------------------------------------------------------
__global__ __launch_bounds__(256) void final_kernel(const __bf16* __restrict__ t2,
                                                    const float* __restrict__ st,
                                                    const float* __restrict__ g,
                                                    const float* __restrict__ bta,
                                                    const float* __restrict__ W3,
                                                    const float* __restrict__ b3,
                                                    float* __restrict__ outp){
    int gid = blockIdx.x*256 + threadIdx.x;
    int wid = gid >> 6, lane = gid & 63;
    int c0 = lane*4;
    bf16x4 v  = *(const bf16x4*)&t2[(size_t)wid*256 + c0];
    float4 w3 = *(const float4*)&W3[c0];
    float4 gg = *(const float4*)&g[c0];
    float4 bb = *(const float4*)&bta[c0];
    float4 sm = *(const float4*)&st[c0];
    float4 sq = *(const float4*)&st[256 + c0];
    float accv = 0.f;
    {
        float mean, var, val;
        mean = sm.x*(1.f/32768.f); var = sq.x*(1.f/32768.f) - mean*mean;
        val = ((float)v[0]-mean)*(gg.x/sqrtf(var+EPSBN)) + bb.x; accv += fmaxf(val,0.f)*w3.x;
        mean = sm.y*(1.f/32768.f); var = sq.y*(1.f/32768.f) - mean*mean;
        val = ((float)v[1]-mean)*(gg.y/sqrtf(var+EPSBN)) + bb.y; accv += fmaxf(val,0.f)*w3.y;
        mean = sm.z*(1.f/32768.f); var = sq.z*(1.f/32768.f) - mean*mean;
        val = ((float)v[2]-mean)*(gg.z/sqrtf(var+EPSBN)) + bb.z; accv += fmaxf(val,0.f)*w3.z;
        mean = sm.w*(1.f/32768.f); var = sq.w*(1.f/32768.f) - mean*mean;
        val = ((float)v[3]-mean)*(gg.w/sqrtf(var+EPSBN)) + bb.w; accv += fmaxf(val,0.f)*w3.w;
    }
    for (int off = 32; off; off >>= 1) accv += __shfl_down(accv, off);
    if (lane == 0) outp[wid] = accv + b3[0];
}

// ---------------------------------------------------------------------------
extern "C" void kernel_launch(void* const* d_in, const int* in_sizes, int n_in,
                              void* d_out, int out_size, void* d_ws, size_t ws_size,
                              hipStream_t stream)
{
    (void)in_sizes; (void)n_in; (void)out_size; (void)ws_size;
    const float* data   = (const float*)d_in[0];
    const float* emb    = (const float*)d_in[1];
    const float* lin_W  = (const float*)d_in[2];
    const float* att_i  = (const float*)d_in[3];
    const float* att_j  = (const float*)d_in[4];
    const float* aem_i  = (const float*)d_in[5];
    const float* aem_j  = (const float*)d_in[6];
    const float* gnn_bias = (const float*)d_in[7];
    const float* gnn_g  = (const float*)d_in[8];
    const float* gnn_b  = (const float*)d_in[9];
    const float* bno_g  = (const float*)d_in[10];
    const float* bno_b  = (const float*)d_in[11];
    const float* W1     = (const float*)d_in[12];
    const float* b1     = (const float*)d_in[13];
    const float* bn1_g  = (const float*)d_in[14];
    const float* bn1_b  = (const float*)d_in[15];
    const float* W2     = (const float*)d_in[16];
    const float* b2     = (const float*)d_in[17];
    const float* bn2_g  = (const float*)d_in[18];
    const float* bn2_b  = (const float*)d_in[19];
    const float* W3     = (const float*)d_in[20];
    const float* b3     = (const float*)d_in[21];
    float* outp = (float*)d_out;
    char*  ws   = (char*)d_ws;

    // workspace layout (bytes)
    int*    topk     = (int*)ws;                        // 64 KB
    float*  e_i      = (float*)(ws + 65536);
    float*  e_j      = (float*)(ws + 67584);
    float*  s_i      = (float*)(ws + 69632);            // 128 KB
    float*  s_j      = (float*)(ws + 200704);           // 128 KB
    float*  stats    = (float*)(ws + 331776);           // 1536 floats
    float*  gnnstats = stats;                           // [256]
    float*  hstats   = stats + 256;                     // [256]
    float*  bn1stats = stats + 512;                     // [512]
    float*  bn2stats = stats + 1024;                    // [512]
    __bf16* Wp1      = (__bf16*)(ws + 337920);          // 64 KB
    __bf16* Wp2      = (__bf16*)(ws + 403456);          // 128 KB
    __bf16* xlin     = (__bf16*)(ws + 1048576);                    // 8 MB
    __bf16* aggb     = (__bf16*)(ws + 1048576 +   8388608);        // 8 MB
    __bf16* t1       = (__bf16*)(ws + 1048576 + 2*8388608);        // 16 MB
    __bf16* t2       = (__bf16*)(ws + 1048576 + 2*8388608 + 16777216); // 16 MB

    // e_i/e_j scalars (tiny)
    escore_kernel<<<8, 256, 0, stream>>>(emb, aem_i, aem_j, e_i, e_j);

    // K1: xlin GEMM (+raw scores) || topk || pack W1/W2 || zero stats
    k1_kernel<<<1073, 256, 0, stream>>>(data, emb, lin_W, W1, W2, att_i, att_j,
                                        topk, Wp1, Wp2, stats, xlin, s_i, s_j);

    // agg (one wave/node, XCD-local batches, + fused gnn column stats)
    agg_kernel<<<8192, 256, 0, stream>>>(xlin, s_i, s_j, e_i, e_j, topk,
                                         (const float2*)gnn_bias, aggb, gnnstats);

    hstats_kernel<<<256, 256, 0, stream>>>(aggb, gnnstats, gnn_g, gnn_b, emb, hstats);

    // t1 = relu(bn_out( relu(bn_gnn(agg))*emb )) @ W1 + b1   (+ bn1 stats)
    gemm2_kernel<true><<<dim3(256,2), 256, 0, stream>>>(
        aggb, 128, 128, gnnstats, gnn_g, gnn_b, emb, hstats, bno_g, bno_b,
        Wp1, 256, b1, t1, bn1stats, 256);

    // t2 = relu(bn1(t1)) @ W2 + b2   (K=256, + bn2 stats)
    gemm2_kernel<false><<<dim3(256,2), 256, 0, stream>>>(
        t1, 256, 256, bn1stats, bn1_g, bn1_b, nullptr, nullptr, nullptr, nullptr,
        Wp2, 256, b2, t2, bn2stats, 256);

    final_kernel<<<M_ROWS/4, 256, 0, stream>>>(t2, bn2stats, bn2_g, bn2_b, W3, b3, outp);
}

// Round 7
// 254.924 us; speedup vs baseline: 1.6924x; 1.6924x over previous
//
#include <hip/hip_runtime.h>
#include <math.h>

// Problem constants (B=64, N=512, F_IN=D=128, K=32, INTER=256)
#define M_ROWS 32768
#define NNODES 512
#define KNBR   32
#define EPSBN  1e-5f

typedef __bf16 bf16x8 __attribute__((ext_vector_type(8)));
typedef __bf16 bf16x4 __attribute__((ext_vector_type(4)));
typedef __bf16 bf16x2 __attribute__((ext_vector_type(2)));
typedef float  f32x4  __attribute__((ext_vector_type(4)));

#if defined(__has_builtin)
#if __has_builtin(__builtin_amdgcn_global_load_lds)
#define HAVE_GLL 1
#endif
#endif

// async global->LDS 16B: LDS dst must be wave-uniform base + lane*16
__device__ __forceinline__ void async_ld16(void* lds, const void* g){
#ifdef HAVE_GLL
    __builtin_amdgcn_global_load_lds((__attribute__((address_space(1))) void*)(g),
                                     (__attribute__((address_space(3))) void*)(lds),
                                     16, 0, 0);
#else
    *(bf16x8*)lds = *(const bf16x8*)g;
#endif
}

// ---------------------------------------------------------------------------
// K1: blocks 0..511    -> xlin GEMM tile (64 rows) + raw score epilogue
//     blocks 512..1023 -> topk row (bid-512) [wave0] + e_i/e_j row [wave1]
//     blocks 1024..1071-> pack W1/W2 to bf16 frag order
//     block  1072      -> zero BN stats
// ---------------------------------------------------------------------------
__global__ __launch_bounds__(256) void k1_kernel(
    const float* __restrict__ data, const float* __restrict__ emb,
    const float* __restrict__ lin_W, const float* __restrict__ W1,
    const float* __restrict__ W2,
    const float* __restrict__ att_i, const float* __restrict__ att_j,
    const float* __restrict__ aem_i, const float* __restrict__ aem_j,
    int* __restrict__ topk, float* __restrict__ e_i, float* __restrict__ e_j,
    __bf16* __restrict__ Wp1, __bf16* __restrict__ Wp2,
    float* __restrict__ stats,
    __bf16* __restrict__ xlin, float* __restrict__ s_i, float* __restrict__ s_j)
{
    __shared__ __align__(16) char sm[50176];   // union: xlin tiles / topk bufs
    int bid = blockIdx.x, tid = threadIdx.x;

    if (bid < 512){
        // ================= xlin GEMM tile =================
        __bf16 (*As)[136] = (__bf16(*)[136])sm;          // 64 x 136
        bf16x8* Bp = (bf16x8*)(sm + 17408);              // 2048 granules
        int lane = tid & 63, wv = tid >> 6;
        int mrow = lane & 15, q = lane >> 4;
        int row0 = bid * 64;

        // self-pack lin_W: Bp[g][j] = lin_W[((g>>7)*8 + j)*128 + (g&127)]
        #pragma unroll
        for (int i = 0; i < 8; ++i){
            int g = tid + i*256;
            int kg = g >> 7, c = g & 127;
            bf16x8 pk;
            #pragma unroll
            for (int j = 0; j < 8; ++j) pk[j] = (__bf16)lin_W[(size_t)(kg*8 + j)*128 + c];
            Bp[g] = pk;
        }
        // stage A fp32 -> bf16
        #pragma unroll
        for (int i = 0; i < 4; ++i){
            int p = tid + i*256;
            int r = p >> 4, c8 = p & 15;
            const float* src = &data[(size_t)(row0 + r)*128 + c8*8];
            float4 a0 = *(const float4*)src;
            float4 a1 = *(const float4*)(src + 4);
            bf16x8 o;
            o[0]=(__bf16)a0.x; o[1]=(__bf16)a0.y; o[2]=(__bf16)a0.z; o[3]=(__bf16)a0.w;
            o[4]=(__bf16)a1.x; o[5]=(__bf16)a1.y; o[6]=(__bf16)a1.z; o[7]=(__bf16)a1.w;
            *(bf16x8*)&As[r][c8*8] = o;
        }
        __syncthreads();

        f32x4 acc[8];
        #pragma unroll
        for (int ct = 0; ct < 8; ++ct) acc[ct] = (f32x4){0.f,0.f,0.f,0.f};
        #pragma unroll
        for (int ks = 0; ks < 4; ++ks){
            bf16x8 a = *(const bf16x8*)&As[wv*16 + mrow][ks*32 + q*8];
            #pragma unroll
            for (int ct = 0; ct < 8; ++ct){
                bf16x8 bb = Bp[(ks*4 + q)*128 + ct*16 + mrow];
                acc[ct] = __builtin_amdgcn_mfma_f32_16x16x32_bf16(a, bb, acc[ct], 0, 0, 0);
            }
        }

        // epilogue: store bf16 + raw attention scores (e_i/e_j added in agg)
        float ai[4] = {0,0,0,0}, aj[4] = {0,0,0,0};
        #pragma unroll
        for (int ct = 0; ct < 8; ++ct){
            int col = ct*16 + mrow;
            float wti = att_i[col], wtj = att_j[col];
            #pragma unroll
            for (int reg = 0; reg < 4; ++reg){
                int row = row0 + wv*16 + q*4 + reg;
                float v = acc[ct][reg];
                xlin[(size_t)row*128 + col] = (__bf16)v;
                ai[reg] += v*wti; aj[reg] += v*wtj;
            }
        }
        #pragma unroll
        for (int mask = 1; mask < 16; mask <<= 1){
            #pragma unroll
            for (int reg = 0; reg < 4; ++reg){
                ai[reg] += __shfl_xor(ai[reg], mask);
                aj[reg] += __shfl_xor(aj[reg], mask);
            }
        }
        if (mrow == 0){
            #pragma unroll
            for (int reg = 0; reg < 4; ++reg){
                int row = row0 + wv*16 + q*4 + reg;
                s_i[row] = ai[reg];
                s_j[row] = aj[reg];
            }
        }
        return;
    }

    if (bid >= 1024){
        if (bid == 1072){
            for (int i = tid; i < 1536; i += 256) stats[i] = 0.f;
            return;
        }
        // pack W1 (4096 granules) then W2 (8192 granules)
        int gidx = (bid - 1024)*256 + tid;            // 0..12287
        const float* W; __bf16* o; int lg;
        if (gidx < 4096){ W = W1; o = Wp1; lg = gidx; }
        else            { W = W2; o = Wp2; lg = gidx - 4096; }
        int kg = lg >> 8, c = lg & 255;
        bf16x8 pk;
        #pragma unroll
        for (int j = 0; j < 8; ++j) pk[j] = (__bf16)W[(size_t)(kg*8 + j)*256 + c];
        *(bf16x8*)&o[(size_t)lg*8] = pk;
        return;
    }

    // ================= topk (wave0) + e-scores (wave1) for row i ==========
    float* wi   = (float*)sm;           // 128
    float* cosv = (float*)(sm + 512);   // 512
    int i = bid - 512;
    if (tid < 128) wi[tid] = emb[i*128 + tid];
    __syncthreads();
    float ni = 0.f;
    #pragma unroll 8
    for (int d = 0; d < 128; ++d) ni += wi[d]*wi[d];
    float rni = sqrtf(ni);
    for (int jj = tid; jj < 512; jj += 256){
        const float4* wj4 = (const float4*)(emb + jj*128);
        float dot = 0.f, nj = 0.f;
        #pragma unroll 8
        for (int d4 = 0; d4 < 32; ++d4){
            float4 w = wj4[d4];
            dot += wi[4*d4+0]*w.x + wi[4*d4+1]*w.y + wi[4*d4+2]*w.z + wi[4*d4+3]*w.w;
            nj  += w.x*w.x + w.y*w.y + w.z*w.z + w.w*w.w;
        }
        cosv[jj] = dot / (rni * sqrtf(nj));
    }
    __syncthreads();
    if (tid < 64){
        int lane = tid;
        float v[8];
        #pragma unroll
        for (int jj = 0; jj < 8; ++jj) v[jj] = cosv[lane + 64*jj];
        for (int k = 0; k < KNBR; ++k){
            float bv = v[0]; int bj = 0;
            #pragma unroll
            for (int jj = 1; jj < 8; ++jj) if (v[jj] > bv){ bv = v[jj]; bj = jj; }
            int bi = lane + 64*bj;
            #pragma unroll
            for (int mask = 1; mask < 64; mask <<= 1){
                float ov = __shfl_xor(bv, mask);
                int   oi = __shfl_xor(bi, mask);
                if (ov > bv || (ov == bv && oi < bi)){ bv = ov; bi = oi; }
            }
            if (lane == 0) topk[i*KNBR + k] = bi;
            if ((bi & 63) == lane){
                int jj = bi >> 6;
                #pragma unroll
                for (int j2 = 0; j2 < 8; ++j2) if (j2 == jj) v[j2] = -2e30f;
            }
        }
    } else if (tid < 128){
        // wave 1: e_i[i] = emb[i].aem_i ; e_j[i] = emb[i].aem_j
        int lane = tid - 64;
        float ai = wi[lane]*aem_i[lane] + wi[lane+64]*aem_i[lane+64];
        float aj = wi[lane]*aem_j[lane] + wi[lane+64]*aem_j[lane+64];
        #pragma unroll
        for (int off = 32; off; off >>= 1){
            ai += __shfl_down(ai, off);
            aj += __shfl_down(aj, off);
        }
        if (lane == 0){ e_i[i] = ai; e_j[i] = aj; }
    }
}

// ---------------------------------------------------------------------------
// agg v4: ONE WAVE per node (8192 blocks x 4 waves), XCD-locality swizzle
// (each XCD gathers from only 8 batch slices -> L2-resident), shuffle softmax,
// bf16 gathers. NO stats fusion (atomic storm lesson, r6).
// ---------------------------------------------------------------------------
__global__ __launch_bounds__(256) void agg_kernel(const __bf16* __restrict__ xl,
                                                  const float* __restrict__ s_i,
                                                  const float* __restrict__ s_j,
                                                  const float* __restrict__ e_i,
                                                  const float* __restrict__ e_j,
                                                  const int* __restrict__ topk,
                                                  const float2* __restrict__ gnn_bias2,
                                                  __bf16* __restrict__ aggp){
    int tid = threadIdx.x;
    int wv = tid >> 6, lane = tid & 63;
    int blk = blockIdx.x;                        // 0..8191
    int xcd = blk & 7, grp = blk >> 3;           // grp 0..1023
    int batch = xcd*8 + (grp >> 7);              // 0..63
    int node  = (grp & 127)*4 + wv;              // 0..511
    int m = batch*512 + node;
    int i = node;

    int src; bool valid;
    if (lane < KNBR){ int j = topk[i*KNBR + lane]; src = batch*512 + j; valid = (j != i); }
    else            { src = m; valid = (lane == KNBR); }
    float l = s_i[m] + e_i[i] + s_j[src] + e_j[src & 511];
    l = (l >= 0.f) ? l : 0.2f*l;                 // leaky_relu 0.2
    l = valid ? l : -1e30f;
    float mx = l;
    #pragma unroll
    for (int mask = 1; mask < 64; mask <<= 1) mx = fmaxf(mx, __shfl_xor(mx, mask));
    float e = valid ? __expf(l - mx) : 0.f;
    float den = e;
    #pragma unroll
    for (int mask = 1; mask < 64; mask <<= 1) den += __shfl_xor(den, mask);
    float alpha = e / den;

    float2 acc = make_float2(0.f, 0.f);
    #pragma unroll 4
    for (int k = 0; k < 33; ++k){
        float a = __shfl(alpha, k);
        int   s = __shfl(src, k);
        bf16x2 v = *(const bf16x2*)&xl[(size_t)s*128 + lane*2];
        acc.x += a*(float)v[0]; acc.y += a*(float)v[1];
    }
    float2 bv = gnn_bias2[lane];
    bf16x2 o;
    o[0] = (__bf16)(acc.x + bv.x);
    o[1] = (__bf16)(acc.y + bv.y);
    *(bf16x2*)&aggp[(size_t)m*128 + lane*2] = o;
}

// ---------------------------------------------------------------------------
// column stats of bf16 [M,128] -> st[0..127]=sum, st[128..255]=sumsq
// 256 blocks -> only 256 atomics/address (known-fine contention level)
// ---------------------------------------------------------------------------
__global__ __launch_bounds__(256) void colstats_kernel(const __bf16* __restrict__ X,
                                                       float* __restrict__ st){
    int tid = threadIdx.x;
    int cg = tid & 31, rs = tid >> 5;
    int c0 = cg*4;
    float s[4] = {0,0,0,0}, qq[4] = {0,0,0,0};
    for (int m = blockIdx.x*8 + rs; m < M_ROWS; m += gridDim.x*8){
        bf16x4 v = *(const bf16x4*)&X[(size_t)m*128 + c0];
        #pragma unroll
        for (int j = 0; j < 4; ++j){ float f = (float)v[j]; s[j] += f; qq[j] += f*f; }
    }
    __shared__ float rS[8][128], rQ[8][128];
    #pragma unroll
    for (int j = 0; j < 4; ++j){ rS[rs][c0+j] = s[j]; rQ[rs][c0+j] = qq[j]; }
    __syncthreads();
    if (tid < 128){
        float ts = 0.f, tq = 0.f;
        #pragma unroll
        for (int u = 0; u < 8; ++u){ ts += rS[u][tid]; tq += rQ[u][tid]; }
        atomicAdd(&st[tid],       ts);
        atomicAdd(&st[128 + tid], tq);
    }
}

// ---------------------------------------------------------------------------
// hstats: h = relu(bn_gnn(agg))*emb computed on the fly (NOT stored);
// accumulate column sum/sumsq of h into hstats.
// ---------------------------------------------------------------------------
__global__ __launch_bounds__(256) void hstats_kernel(const __bf16* __restrict__ agg,
                                                     const float* __restrict__ gst,
                                                     const float* __restrict__ g,
                                                     const float* __restrict__ bta,
                                                     const float* __restrict__ emb,
                                                     float* __restrict__ hstats){
    int tid = threadIdx.x;
    int cg = tid & 31, rs = tid >> 5;
    int c0 = cg*4;
    float sc[4], sh[4];
    #pragma unroll
    for (int j = 0; j < 4; ++j){
        float mean = gst[c0+j] * (1.f/32768.f);
        float var  = gst[128 + c0+j] * (1.f/32768.f) - mean*mean;
        sc[j] = g[c0+j] / sqrtf(var + EPSBN);
        sh[j] = bta[c0+j] - mean*sc[j];
    }
    float s[4] = {0,0,0,0}, qq[4] = {0,0,0,0};
    for (int m = blockIdx.x*8 + rs; m < M_ROWS; m += gridDim.x*8){
        bf16x4 v = *(const bf16x4*)&agg[(size_t)m*128 + c0];
        float4 e = *(const float4*)&emb[(size_t)(m & 511)*128 + c0];
        float f0 = fmaxf((float)v[0]*sc[0] + sh[0], 0.f) * e.x;
        float f1 = fmaxf((float)v[1]*sc[1] + sh[1], 0.f) * e.y;
        float f2 = fmaxf((float)v[2]*sc[2] + sh[2], 0.f) * e.z;
        float f3 = fmaxf((float)v[3]*sc[3] + sh[3], 0.f) * e.w;
        s[0]+=f0; qq[0]+=f0*f0; s[1]+=f1; qq[1]+=f1*f1;
        s[2]+=f2; qq[2]+=f2*f2; s[3]+=f3; qq[3]+=f3*f3;
    }
    __shared__ float rS[8][128], rQ[8][128];
    #pragma unroll
    for (int j = 0; j < 4; ++j){ rS[rs][c0+j] = s[j]; rQ[rs][c0+j] = qq[j]; }
    __syncthreads();
    if (tid < 128){
        float ts = 0.f, tq = 0.f;
        #pragma unroll
        for (int u = 0; u < 8; ++u){ ts += rS[u][tid]; tq += rQ[u][tid]; }
        atomicAdd(&hstats[tid],       ts);
        atomicAdd(&hstats[128 + tid], tq);
    }
}

// ---------------------------------------------------------------------------
// bf16 MFMA GEMM (128x128 tile, 2x2 wave grid).
// GATE: A-staging = relu(bn_out( relu(bn_gnn(agg)) * emb )), K=128
// else: A-staging = relu(bn1(t1)), K=256
// ---------------------------------------------------------------------------
template<bool GATE>
__global__ __launch_bounds__(256) void gemm2_kernel(
    const __bf16* __restrict__ A, int a_stride, int Ktot,
    const float* __restrict__ st1, const float* __restrict__ g1, const float* __restrict__ b1,
    const float* __restrict__ emb,
    const float* __restrict__ st2, const float* __restrict__ g2, const float* __restrict__ b2,
    const __bf16* __restrict__ Wp, int Ctot,
    const float* __restrict__ bias,
    __bf16* __restrict__ outp,
    float* __restrict__ outstats, int outK)
{
    __shared__ __align__(16) __bf16 As[128][136];
    __shared__ __align__(16) __bf16 Bp[16][128][8];
    __shared__ float nsc1[128], nsh1[128], nsc2[128], nsh2[128];
    __shared__ float statS[128], statQ[128];

    int tid  = threadIdx.x;
    int lane = tid & 63, wv = tid >> 6;
    int mrow = lane & 15, q = lane >> 4;
    int wvr = wv & 1, wvc = wv >> 1;             // 2x2 wave grid
    int cb0  = blockIdx.y * 128;
    int row0 = blockIdx.x * 128;

    f32x4 acc[4][4];
    #pragma unroll
    for (int rt = 0; rt < 4; ++rt)
        #pragma unroll
        for (int ct = 0; ct < 4; ++ct)
            acc[rt][ct] = (f32x4){0.f,0.f,0.f,0.f};

    for (int kc = 0; kc < Ktot; kc += 128){
        if (tid < 128){
            int f = kc + tid;
            float mean = st1[f] * (1.f/32768.f);
            float var  = st1[Ktot + f] * (1.f/32768.f) - mean*mean;
            float sc   = g1[f] / sqrtf(var + EPSBN);
            nsc1[tid] = sc;
            nsh1[tid] = b1[f] - mean*sc;
            if (GATE){
                float mean2 = st2[tid] * (1.f/32768.f);
                float var2  = st2[128 + tid] * (1.f/32768.f) - mean2*mean2;
                float sc2   = g2[tid] / sqrtf(var2 + EPSBN);
                nsc2[tid] = sc2;
                nsh2[tid] = b2[tid] - mean2*sc2;
            }
        }
        __syncthreads();

        // B: async 16B granules into LDS (pre-packed frag order)
        int kg0 = kc >> 3;
        #pragma unroll
        for (int i = 0; i < 8; ++i){
            int p = tid + i*256;
            const __bf16* src = Wp + ((size_t)(kg0 + (p>>7))*Ctot + cb0 + (p&127))*8;
            async_ld16((__bf16*)Bp + (size_t)p*8, src);
        }
        // A: through regs with fused activation chain
        #pragma unroll
        for (int i = 0; i < 8; ++i){
            int p = tid + i*256;
            int r = p >> 4, c8 = p & 15;
            bf16x8 v = *(const bf16x8*)&A[(size_t)(row0 + r)*a_stride + kc + c8*8];
            bf16x8 o;
            if (GATE){
                const float* ep = &emb[(size_t)((row0 + r) & 511)*128 + c8*8];
                float4 e0 = *(const float4*)ep;
                float4 e1 = *(const float4*)(ep + 4);
                float ee[8] = {e0.x,e0.y,e0.z,e0.w,e1.x,e1.y,e1.z,e1.w};
                #pragma unroll
                for (int j = 0; j < 8; ++j){
                    int f = c8*8 + j;
                    float hv = fmaxf((float)v[j]*nsc1[f] + nsh1[f], 0.f) * ee[j];
                    o[j] = (__bf16)fmaxf(hv*nsc2[f] + nsh2[f], 0.f);
                }
            } else {
                #pragma unroll
                for (int j = 0; j < 8; ++j){
                    int f = c8*8 + j;
                    o[j] = (__bf16)fmaxf((float)v[j]*nsc1[f] + nsh1[f], 0.f);
                }
            }
            *(bf16x8*)&As[r][c8*8] = o;
        }
        __syncthreads();

        #pragma unroll
        for (int ks = 0; ks < 4; ++ks){
            bf16x8 a[4];
            #pragma unroll
            for (int rt = 0; rt < 4; ++rt)
                a[rt] = *(const bf16x8*)&As[wvr*64 + rt*16 + mrow][ks*32 + q*8];
            #pragma unroll
            for (int ct = 0; ct < 4; ++ct){
                bf16x8 bb = *(const bf16x8*)&Bp[ks*4 + q][wvc*64 + ct*16 + mrow][0];
                #pragma unroll
                for (int rt = 0; rt < 4; ++rt)
                    acc[rt][ct] = __builtin_amdgcn_mfma_f32_16x16x32_bf16(a[rt], bb, acc[rt][ct], 0, 0, 0);
            }
        }
        __syncthreads();
    }

    if (tid < 128){ statS[tid] = 0.f; statQ[tid] = 0.f; }
    __syncthreads();

    float cs[4] = {0,0,0,0}, cq[4] = {0,0,0,0};
    #pragma unroll
    for (int ct = 0; ct < 4; ++ct){
        int lcol = wvc*64 + ct*16 + mrow;
        int col  = cb0 + lcol;
        float bvv = bias[col];
        #pragma unroll
        for (int rt = 0; rt < 4; ++rt){
            #pragma unroll
            for (int reg = 0; reg < 4; ++reg){
                int row = row0 + wvr*64 + rt*16 + q*4 + reg;
                __bf16 ov = (__bf16)(acc[rt][ct][reg] + bvv);
                outp[(size_t)row*Ctot + col] = ov;
                float fv = (float)ov; cs[ct] += fv; cq[ct] += fv*fv;
            }
        }
    }
    #pragma unroll
    for (int ct = 0; ct < 4; ++ct){
        float s  = cs[ct]; s  += __shfl_xor(s, 16);  s  += __shfl_xor(s, 32);
        float qq = cq[ct]; qq += __shfl_xor(qq, 16); qq += __shfl_xor(qq, 32);
        if (q == 0){
            atomicAdd(&statS[wvc*64 + ct*16 + mrow], s);
            atomicAdd(&statQ[wvc*64 + ct*16 + mrow], qq);
        }
    }
    __syncthreads();
    if (tid < 128){
        atomicAdd(&outstats[cb0 + tid],        statS[tid]);
        atomicAdd(&outstats[outK + cb0 + tid], statQ[tid]);
    }
}

// ---------------------------------------------------------------------------
// out[m] = relu(bn2(t2[m,:])) . W3 + b3   (one wave per row, bf16 in, f32 out)
// ---------------------------------------------------------------------------
__global__ __launch_bounds__(256) void final_kernel(const __bf16* __restrict__ t2,
                                                    const float* __restrict__ st,
                                                    const float* __restrict__ g,
                                                    const float* __restrict__ bta,
                                                    const float* __restrict__ W3,
                                                    const float* __restrict__ b3,
                                                    float* __restrict__ outp){
    int gid = blockIdx.x*256 + threadIdx.x;
    int wid = gid >> 6, lane = gid & 63;
    int c0 = lane*4;
    bf16x4 v  = *(const bf16x4*)&t2[(size_t)wid*256 + c0];
    float4 w3 = *(const float4*)&W3[c0];
    float4 gg = *(const float4*)&g[c0];
    float4 bb = *(const float4*)&bta[c0];
    float4 sm = *(const float4*)&st[c0];
    float4 sq = *(const float4*)&st[256 + c0];
    float accv = 0.f;
    {
        float mean, var, val;
        mean = sm.x*(1.f/32768.f); var = sq.x*(1.f/32768.f) - mean*mean;
        val = ((float)v[0]-mean)*(gg.x/sqrtf(var+EPSBN)) + bb.x; accv += fmaxf(val,0.f)*w3.x;
        mean = sm.y*(1.f/32768.f); var = sq.y*(1.f/32768.f) - mean*mean;
        val = ((float)v[1]-mean)*(gg.y/sqrtf(var+EPSBN)) + bb.y; accv += fmaxf(val,0.f)*w3.y;
        mean = sm.z*(1.f/32768.f); var = sq.z*(1.f/32768.f) - mean*mean;
        val = ((float)v[2]-mean)*(gg.z/sqrtf(var+EPSBN)) + bb.z; accv += fmaxf(val,0.f)*w3.z;
        mean = sm.w*(1.f/32768.f); var = sq.w*(1.f/32768.f) - mean*mean;
        val = ((float)v[3]-mean)*(gg.w/sqrtf(var+EPSBN)) + bb.w; accv += fmaxf(val,0.f)*w3.w;
    }
    for (int off = 32; off; off >>= 1) accv += __shfl_down(accv, off);
    if (lane == 0) outp[wid] = accv + b3[0];
}

// ---------------------------------------------------------------------------
extern "C" void kernel_launch(void* const* d_in, const int* in_sizes, int n_in,
                              void* d_out, int out_size, void* d_ws, size_t ws_size,
                              hipStream_t stream)
{
    (void)in_sizes; (void)n_in; (void)out_size; (void)ws_size;
    const float* data   = (const float*)d_in[0];
    const float* emb    = (const float*)d_in[1];
    const float* lin_W  = (const float*)d_in[2];
    const float* att_i  = (const float*)d_in[3];
    const float* att_j  = (const float*)d_in[4];
    const float* aem_i  = (const float*)d_in[5];
    const float* aem_j  = (const float*)d_in[6];
    const float* gnn_bias = (const float*)d_in[7];
    const float* gnn_g  = (const float*)d_in[8];
    const float* gnn_b  = (const float*)d_in[9];
    const float* bno_g  = (const float*)d_in[10];
    const float* bno_b  = (const float*)d_in[11];
    const float* W1     = (const float*)d_in[12];
    const float* b1     = (const float*)d_in[13];
    const float* bn1_g  = (const float*)d_in[14];
    const float* bn1_b  = (const float*)d_in[15];
    const float* W2     = (const float*)d_in[16];
    const float* b2     = (const float*)d_in[17];
    const float* bn2_g  = (const float*)d_in[18];
    const float* bn2_b  = (const float*)d_in[19];
    const float* W3     = (const float*)d_in[20];
    const float* b3     = (const float*)d_in[21];
    float* outp = (float*)d_out;
    char*  ws   = (char*)d_ws;

    // workspace layout (bytes)
    int*    topk     = (int*)ws;                        // 64 KB
    float*  e_i      = (float*)(ws + 65536);
    float*  e_j      = (float*)(ws + 67584);
    float*  s_i      = (float*)(ws + 69632);            // 128 KB
    float*  s_j      = (float*)(ws + 200704);           // 128 KB
    float*  stats    = (float*)(ws + 331776);           // 1536 floats
    float*  gnnstats = stats;                           // [256]
    float*  hstats   = stats + 256;                     // [256]
    float*  bn1stats = stats + 512;                     // [512]
    float*  bn2stats = stats + 1024;                    // [512]
    __bf16* Wp1      = (__bf16*)(ws + 337920);          // 64 KB
    __bf16* Wp2      = (__bf16*)(ws + 403456);          // 128 KB
    __bf16* xlin     = (__bf16*)(ws + 1048576);                    // 8 MB
    __bf16* aggb     = (__bf16*)(ws + 1048576 +   8388608);        // 8 MB
    __bf16* t1       = (__bf16*)(ws + 1048576 + 2*8388608);        // 16 MB
    __bf16* t2       = (__bf16*)(ws + 1048576 + 2*8388608 + 16777216); // 16 MB

    // K1: xlin GEMM (+raw scores) || topk+e-scores || pack W1/W2 || zero stats
    k1_kernel<<<1073, 256, 0, stream>>>(data, emb, lin_W, W1, W2, att_i, att_j,
                                        aem_i, aem_j, topk, e_i, e_j,
                                        Wp1, Wp2, stats, xlin, s_i, s_j);

    // agg (one wave/node, XCD-local batches, NO fused stats)
    agg_kernel<<<8192, 256, 0, stream>>>(xlin, s_i, s_j, e_i, e_j, topk,
                                         (const float2*)gnn_bias, aggb);

    colstats_kernel<<<256, 256, 0, stream>>>(aggb, gnnstats);
    hstats_kernel<<<256, 256, 0, stream>>>(aggb, gnnstats, gnn_g, gnn_b, emb, hstats);

    // t1 = relu(bn_out( relu(bn_gnn(agg))*emb )) @ W1 + b1   (+ bn1 stats)
    gemm2_kernel<true><<<dim3(256,2), 256, 0, stream>>>(
        aggb, 128, 128, gnnstats, gnn_g, gnn_b, emb, hstats, bno_g, bno_b,
        Wp1, 256, b1, t1, bn1stats, 256);

    // t2 = relu(bn1(t1)) @ W2 + b2   (K=256, + bn2 stats)
    gemm2_kernel<false><<<dim3(256,2), 256, 0, stream>>>(
        t1, 256, 256, bn1stats, bn1_g, bn1_b, nullptr, nullptr, nullptr, nullptr,
        Wp2, 256, b2, t2, bn2stats, 256);

    final_kernel<<<M_ROWS/4, 256, 0, stream>>>(t2, bn2stats, bn2_g, bn2_b, W3, b3, outp);
}

// Round 8
// 246.601 us; speedup vs baseline: 1.7495x; 1.0338x over previous
//
#include <hip/hip_runtime.h>
#include <math.h>

// Problem constants (B=64, N=512, F_IN=D=128, K=32, INTER=256)
#define M_ROWS 32768
#define NNODES 512
#define KNBR   32
#define EPSBN  1e-5f

typedef __bf16 bf16x8 __attribute__((ext_vector_type(8)));
typedef __bf16 bf16x4 __attribute__((ext_vector_type(4)));
typedef __bf16 bf16x2 __attribute__((ext_vector_type(2)));
typedef float  f32x4  __attribute__((ext_vector_type(4)));

#if defined(__has_builtin)
#if __has_builtin(__builtin_amdgcn_global_load_lds)
#define HAVE_GLL 1
#endif
#endif

// async global->LDS 16B: LDS dst must be wave-uniform base + lane*16
__device__ __forceinline__ void async_ld16(void* lds, const void* g){
#ifdef HAVE_GLL
    __builtin_amdgcn_global_load_lds((__attribute__((address_space(1))) void*)(g),
                                     (__attribute__((address_space(3))) void*)(lds),
                                     16, 0, 0);
#else
    *(bf16x8*)lds = *(const bf16x8*)g;
#endif
}

// ---------------------------------------------------------------------------
// K1: blocks 0..511    -> xlin GEMM tile (64 rows) + raw score epilogue
//     blocks 512..1023 -> topk row (bitonic sort, all 256 thr) + e-scores
//     blocks 1024..1071-> pack W1/W2 to bf16 frag order
//     block  1072      -> zero BN stats
// ---------------------------------------------------------------------------
__global__ __launch_bounds__(256) void k1_kernel(
    const float* __restrict__ data, const float* __restrict__ emb,
    const float* __restrict__ lin_W, const float* __restrict__ W1,
    const float* __restrict__ W2,
    const float* __restrict__ att_i, const float* __restrict__ att_j,
    const float* __restrict__ aem_i, const float* __restrict__ aem_j,
    int* __restrict__ topk, float* __restrict__ e_i, float* __restrict__ e_j,
    __bf16* __restrict__ Wp1, __bf16* __restrict__ Wp2,
    float* __restrict__ stats,
    __bf16* __restrict__ xlin, float* __restrict__ s_i, float* __restrict__ s_j)
{
    __shared__ __align__(16) char sm[50176];   // union: xlin tiles / topk bufs
    int bid = blockIdx.x, tid = threadIdx.x;

    if (bid < 512){
        // ================= xlin GEMM tile =================
        __bf16 (*As)[136] = (__bf16(*)[136])sm;          // 64 x 136
        bf16x8* Bp = (bf16x8*)(sm + 17408);              // 2048 granules
        int lane = tid & 63, wv = tid >> 6;
        int mrow = lane & 15, q = lane >> 4;
        int row0 = bid * 64;

        // self-pack lin_W: Bp[g][j] = lin_W[((g>>7)*8 + j)*128 + (g&127)]
        #pragma unroll
        for (int i = 0; i < 8; ++i){
            int g = tid + i*256;
            int kg = g >> 7, c = g & 127;
            bf16x8 pk;
            #pragma unroll
            for (int j = 0; j < 8; ++j) pk[j] = (__bf16)lin_W[(size_t)(kg*8 + j)*128 + c];
            Bp[g] = pk;
        }
        // stage A fp32 -> bf16
        #pragma unroll
        for (int i = 0; i < 4; ++i){
            int p = tid + i*256;
            int r = p >> 4, c8 = p & 15;
            const float* src = &data[(size_t)(row0 + r)*128 + c8*8];
            float4 a0 = *(const float4*)src;
            float4 a1 = *(const float4*)(src + 4);
            bf16x8 o;
            o[0]=(__bf16)a0.x; o[1]=(__bf16)a0.y; o[2]=(__bf16)a0.z; o[3]=(__bf16)a0.w;
            o[4]=(__bf16)a1.x; o[5]=(__bf16)a1.y; o[6]=(__bf16)a1.z; o[7]=(__bf16)a1.w;
            *(bf16x8*)&As[r][c8*8] = o;
        }
        __syncthreads();

        f32x4 acc[8];
        #pragma unroll
        for (int ct = 0; ct < 8; ++ct) acc[ct] = (f32x4){0.f,0.f,0.f,0.f};
        #pragma unroll
        for (int ks = 0; ks < 4; ++ks){
            bf16x8 a = *(const bf16x8*)&As[wv*16 + mrow][ks*32 + q*8];
            #pragma unroll
            for (int ct = 0; ct < 8; ++ct){
                bf16x8 bb = Bp[(ks*4 + q)*128 + ct*16 + mrow];
                acc[ct] = __builtin_amdgcn_mfma_f32_16x16x32_bf16(a, bb, acc[ct], 0, 0, 0);
            }
        }

        // epilogue: store bf16 + raw attention scores (e_i/e_j added in agg)
        float ai[4] = {0,0,0,0}, aj[4] = {0,0,0,0};
        #pragma unroll
        for (int ct = 0; ct < 8; ++ct){
            int col = ct*16 + mrow;
            float wti = att_i[col], wtj = att_j[col];
            #pragma unroll
            for (int reg = 0; reg < 4; ++reg){
                int row = row0 + wv*16 + q*4 + reg;
                float v = acc[ct][reg];
                xlin[(size_t)row*128 + col] = (__bf16)v;
                ai[reg] += v*wti; aj[reg] += v*wtj;
            }
        }
        #pragma unroll
        for (int mask = 1; mask < 16; mask <<= 1){
            #pragma unroll
            for (int reg = 0; reg < 4; ++reg){
                ai[reg] += __shfl_xor(ai[reg], mask);
                aj[reg] += __shfl_xor(aj[reg], mask);
            }
        }
        if (mrow == 0){
            #pragma unroll
            for (int reg = 0; reg < 4; ++reg){
                int row = row0 + wv*16 + q*4 + reg;
                s_i[row] = ai[reg];
                s_j[row] = aj[reg];
            }
        }
        return;
    }

    if (bid >= 1024){
        if (bid == 1072){
            for (int i = tid; i < 1536; i += 256) stats[i] = 0.f;
            return;
        }
        // pack W1 (4096 granules) then W2 (8192 granules)
        int gidx = (bid - 1024)*256 + tid;            // 0..12287
        const float* W; __bf16* o; int lg;
        if (gidx < 4096){ W = W1; o = Wp1; lg = gidx; }
        else            { W = W2; o = Wp2; lg = gidx - 4096; }
        int kg = lg >> 8, c = lg & 255;
        bf16x8 pk;
        #pragma unroll
        for (int j = 0; j < 8; ++j) pk[j] = (__bf16)W[(size_t)(kg*8 + j)*256 + c];
        *(bf16x8*)&o[(size_t)lg*8] = pk;
        return;
    }

    // ============ topk via bitonic sort (all 256 thr) + e-scores ==========
    float* wi   = (float*)sm;            // 128 floats
    float* sval = (float*)(sm + 512);    // 512 floats (cos values)
    int*   sidx = (int*)(sm + 2560);     // 512 ints
    int row = bid - 512;
    if (tid < 128) wi[tid] = emb[row*128 + tid];
    __syncthreads();

    // wave 1: e_i[row], e_j[row] (overlaps cos loop below)
    if (tid >= 64 && tid < 128){
        int lane = tid - 64;
        float ai = wi[lane]*aem_i[lane] + wi[lane+64]*aem_i[lane+64];
        float aj = wi[lane]*aem_j[lane] + wi[lane+64]*aem_j[lane+64];
        #pragma unroll
        for (int off = 32; off; off >>= 1){
            ai += __shfl_down(ai, off);
            aj += __shfl_down(aj, off);
        }
        if (lane == 0){ e_i[row] = ai; e_j[row] = aj; }
    }

    float ni = 0.f;
    #pragma unroll 8
    for (int d = 0; d < 128; ++d) ni += wi[d]*wi[d];
    float rni = sqrtf(ni);
    for (int jj = tid; jj < 512; jj += 256){
        const float4* wj4 = (const float4*)(emb + jj*128);
        float dot = 0.f, nj = 0.f;
        #pragma unroll 8
        for (int d4 = 0; d4 < 32; ++d4){
            float4 w = wj4[d4];
            dot += wi[4*d4+0]*w.x + wi[4*d4+1]*w.y + wi[4*d4+2]*w.z + wi[4*d4+3]*w.w;
            nj  += w.x*w.x + w.y*w.y + w.z*w.z + w.w*w.w;
        }
        sval[jj] = dot / (rni * sqrtf(nj));
        sidx[jj] = jj;
    }
    __syncthreads();

    // bitonic sort: strict order (value desc, index asc) == jax.lax.top_k
    #pragma unroll 1
    for (int k = 2; k <= 512; k <<= 1){
        #pragma unroll 1
        for (int j = k >> 1; j > 0; j >>= 1){
            int i2 = ((tid & ~(j-1)) << 1) | (tid & (j-1));
            int p  = i2 | j;
            float vi = sval[i2], vp = sval[p];
            int   xi = sidx[i2], xp = sidx[p];
            bool i_before_p = (vi > vp) || (vi == vp && xi < xp);
            bool up = ((i2 & k) == 0);
            if (up ? !i_before_p : i_before_p){
                sval[i2] = vp; sval[p] = vi;
                sidx[i2] = xp; sidx[p] = xi;
            }
            __syncthreads();
        }
    }
    if (tid < KNBR) topk[row*KNBR + tid] = sidx[tid];
}

// ---------------------------------------------------------------------------
// agg v4: ONE WAVE per node (8192 blocks x 4 waves), XCD-locality swizzle
// (each XCD gathers from only 8 batch slices -> L2-resident), shuffle softmax,
// bf16 gathers. NO stats fusion (atomic storm lesson, r6).
// ---------------------------------------------------------------------------
__global__ __launch_bounds__(256) void agg_kernel(const __bf16* __restrict__ xl,
                                                  const float* __restrict__ s_i,
                                                  const float* __restrict__ s_j,
                                                  const float* __restrict__ e_i,
                                                  const float* __restrict__ e_j,
                                                  const int* __restrict__ topk,
                                                  const float2* __restrict__ gnn_bias2,
                                                  __bf16* __restrict__ aggp){
    int tid = threadIdx.x;
    int wv = tid >> 6, lane = tid & 63;
    int blk = blockIdx.x;                        // 0..8191
    int xcd = blk & 7, grp = blk >> 3;           // grp 0..1023
    int batch = xcd*8 + (grp >> 7);              // 0..63
    int node  = (grp & 127)*4 + wv;              // 0..511
    int m = batch*512 + node;
    int i = node;

    int src; bool valid;
    if (lane < KNBR){ int j = topk[i*KNBR + lane]; src = batch*512 + j; valid = (j != i); }
    else            { src = m; valid = (lane == KNBR); }
    float l = s_i[m] + e_i[i] + s_j[src] + e_j[src & 511];
    l = (l >= 0.f) ? l : 0.2f*l;                 // leaky_relu 0.2
    l = valid ? l : -1e30f;
    float mx = l;
    #pragma unroll
    for (int mask = 1; mask < 64; mask <<= 1) mx = fmaxf(mx, __shfl_xor(mx, mask));
    float e = valid ? __expf(l - mx) : 0.f;
    float den = e;
    #pragma unroll
    for (int mask = 1; mask < 64; mask <<= 1) den += __shfl_xor(den, mask);
    float alpha = e / den;

    float2 acc = make_float2(0.f, 0.f);
    #pragma unroll 4
    for (int k = 0; k < 33; ++k){
        float a = __shfl(alpha, k);
        int   s = __shfl(src, k);
        bf16x2 v = *(const bf16x2*)&xl[(size_t)s*128 + lane*2];
        acc.x += a*(float)v[0]; acc.y += a*(float)v[1];
    }
    float2 bv = gnn_bias2[lane];
    bf16x2 o;
    o[0] = (__bf16)(acc.x + bv.x);
    o[1] = (__bf16)(acc.y + bv.y);
    *(bf16x2*)&aggp[(size_t)m*128 + lane*2] = o;
}

// ---------------------------------------------------------------------------
// column stats of bf16 [M,128] -> st[0..127]=sum, st[128..255]=sumsq
// 256 blocks -> only 256 atomics/address (known-fine contention level)
// ---------------------------------------------------------------------------
__global__ __launch_bounds__(256) void colstats_kernel(const __bf16* __restrict__ X,
                                                       float* __restrict__ st){
    int tid = threadIdx.x;
    int cg = tid & 31, rs = tid >> 5;
    int c0 = cg*4;
    float s[4] = {0,0,0,0}, qq[4] = {0,0,0,0};
    for (int m = blockIdx.x*8 + rs; m < M_ROWS; m += gridDim.x*8){
        bf16x4 v = *(const bf16x4*)&X[(size_t)m*128 + c0];
        #pragma unroll
        for (int j = 0; j < 4; ++j){ float f = (float)v[j]; s[j] += f; qq[j] += f*f; }
    }
    __shared__ float rS[8][128], rQ[8][128];
    #pragma unroll
    for (int j = 0; j < 4; ++j){ rS[rs][c0+j] = s[j]; rQ[rs][c0+j] = qq[j]; }
    __syncthreads();
    if (tid < 128){
        float ts = 0.f, tq = 0.f;
        #pragma unroll
        for (int u = 0; u < 8; ++u){ ts += rS[u][tid]; tq += rQ[u][tid]; }
        atomicAdd(&st[tid],       ts);
        atomicAdd(&st[128 + tid], tq);
    }
}

// ---------------------------------------------------------------------------
// hstats: h = relu(bn_gnn(agg))*emb computed on the fly (NOT stored);
// accumulate column sum/sumsq of h into hstats.
// ---------------------------------------------------------------------------
__global__ __launch_bounds__(256) void hstats_kernel(const __bf16* __restrict__ agg,
                                                     const float* __restrict__ gst,
                                                     const float* __restrict__ g,
                                                     const float* __restrict__ bta,
                                                     const float* __restrict__ emb,
                                                     float* __restrict__ hstats){
    int tid = threadIdx.x;
    int cg = tid & 31, rs = tid >> 5;
    int c0 = cg*4;
    float sc[4], sh[4];
    #pragma unroll
    for (int j = 0; j < 4; ++j){
        float mean = gst[c0+j] * (1.f/32768.f);
        float var  = gst[128 + c0+j] * (1.f/32768.f) - mean*mean;
        sc[j] = g[c0+j] / sqrtf(var + EPSBN);
        sh[j] = bta[c0+j] - mean*sc[j];
    }
    float s[4] = {0,0,0,0}, qq[4] = {0,0,0,0};
    for (int m = blockIdx.x*8 + rs; m < M_ROWS; m += gridDim.x*8){
        bf16x4 v = *(const bf16x4*)&agg[(size_t)m*128 + c0];
        float4 e = *(const float4*)&emb[(size_t)(m & 511)*128 + c0];
        float f0 = fmaxf((float)v[0]*sc[0] + sh[0], 0.f) * e.x;
        float f1 = fmaxf((float)v[1]*sc[1] + sh[1], 0.f) * e.y;
        float f2 = fmaxf((float)v[2]*sc[2] + sh[2], 0.f) * e.z;
        float f3 = fmaxf((float)v[3]*sc[3] + sh[3], 0.f) * e.w;
        s[0]+=f0; qq[0]+=f0*f0; s[1]+=f1; qq[1]+=f1*f1;
        s[2]+=f2; qq[2]+=f2*f2; s[3]+=f3; qq[3]+=f3*f3;
    }
    __shared__ float rS[8][128], rQ[8][128];
    #pragma unroll
    for (int j = 0; j < 4; ++j){ rS[rs][c0+j] = s[j]; rQ[rs][c0+j] = qq[j]; }
    __syncthreads();
    if (tid < 128){
        float ts = 0.f, tq = 0.f;
        #pragma unroll
        for (int u = 0; u < 8; ++u){ ts += rS[u][tid]; tq += rQ[u][tid]; }
        atomicAdd(&hstats[tid],       ts);
        atomicAdd(&hstats[128 + tid], tq);
    }
}

// ---------------------------------------------------------------------------
// bf16 MFMA GEMM (128x128 tile, 2x2 wave grid).
// GATE: A-staging = relu(bn_out( relu(bn_gnn(agg)) * emb )), K=128
// else: A-staging = relu(bn1(t1)), K=256
// ---------------------------------------------------------------------------
template<bool GATE>
__global__ __launch_bounds__(256) void gemm2_kernel(
    const __bf16* __restrict__ A, int a_stride, int Ktot,
    const float* __restrict__ st1, const float* __restrict__ g1, const float* __restrict__ b1,
    const float* __restrict__ emb,
    const float* __restrict__ st2, const float* __restrict__ g2, const float* __restrict__ b2,
    const __bf16* __restrict__ Wp, int Ctot,
    const float* __restrict__ bias,
    __bf16* __restrict__ outp,
    float* __restrict__ outstats, int outK)
{
    __shared__ __align__(16) __bf16 As[128][136];
    __shared__ __align__(16) __bf16 Bp[16][128][8];
    __shared__ float nsc1[128], nsh1[128], nsc2[128], nsh2[128];
    __shared__ float statS[128], statQ[128];

    int tid  = threadIdx.x;
    int lane = tid & 63, wv = tid >> 6;
    int mrow = lane & 15, q = lane >> 4;
    int wvr = wv & 1, wvc = wv >> 1;             // 2x2 wave grid
    int cb0  = blockIdx.y * 128;
    int row0 = blockIdx.x * 128;

    f32x4 acc[4][4];
    #pragma unroll
    for (int rt = 0; rt < 4; ++rt)
        #pragma unroll
        for (int ct = 0; ct < 4; ++ct)
            acc[rt][ct] = (f32x4){0.f,0.f,0.f,0.f};

    for (int kc = 0; kc < Ktot; kc += 128){
        if (tid < 128){
            int f = kc + tid;
            float mean = st1[f] * (1.f/32768.f);
            float var  = st1[Ktot + f] * (1.f/32768.f) - mean*mean;
            float sc   = g1[f] / sqrtf(var + EPSBN);
            nsc1[tid] = sc;
            nsh1[tid] = b1[f] - mean*sc;
            if (GATE){
                float mean2 = st2[tid] * (1.f/32768.f);
                float var2  = st2[128 + tid] * (1.f/32768.f) - mean2*mean2;
                float sc2   = g2[tid] / sqrtf(var2 + EPSBN);
                nsc2[tid] = sc2;
                nsh2[tid] = b2[tid] - mean2*sc2;
            }
        }
        __syncthreads();

        // B: async 16B granules into LDS (pre-packed frag order)
        int kg0 = kc >> 3;
        #pragma unroll
        for (int i = 0; i < 8; ++i){
            int p = tid + i*256;
            const __bf16* src = Wp + ((size_t)(kg0 + (p>>7))*Ctot + cb0 + (p&127))*8;
            async_ld16((__bf16*)Bp + (size_t)p*8, src);
        }
        // A: through regs with fused activation chain
        #pragma unroll
        for (int i = 0; i < 8; ++i){
            int p = tid + i*256;
            int r = p >> 4, c8 = p & 15;
            bf16x8 v = *(const bf16x8*)&A[(size_t)(row0 + r)*a_stride + kc + c8*8];
            bf16x8 o;
            if (GATE){
                const float* ep = &emb[(size_t)((row0 + r) & 511)*128 + c8*8];
                float4 e0 = *(const float4*)ep;
                float4 e1 = *(const float4*)(ep + 4);
                float ee[8] = {e0.x,e0.y,e0.z,e0.w,e1.x,e1.y,e1.z,e1.w};
                #pragma unroll
                for (int j = 0; j < 8; ++j){
                    int f = c8*8 + j;
                    float hv = fmaxf((float)v[j]*nsc1[f] + nsh1[f], 0.f) * ee[j];
                    o[j] = (__bf16)fmaxf(hv*nsc2[f] + nsh2[f], 0.f);
                }
            } else {
                #pragma unroll
                for (int j = 0; j < 8; ++j){
                    int f = c8*8 + j;
                    o[j] = (__bf16)fmaxf((float)v[j]*nsc1[f] + nsh1[f], 0.f);
                }
            }
            *(bf16x8*)&As[r][c8*8] = o;
        }
        __syncthreads();

        #pragma unroll
        for (int ks = 0; ks < 4; ++ks){
            bf16x8 a[4];
            #pragma unroll
            for (int rt = 0; rt < 4; ++rt)
                a[rt] = *(const bf16x8*)&As[wvr*64 + rt*16 + mrow][ks*32 + q*8];
            #pragma unroll
            for (int ct = 0; ct < 4; ++ct){
                bf16x8 bb = *(const bf16x8*)&Bp[ks*4 + q][wvc*64 + ct*16 + mrow][0];
                #pragma unroll
                for (int rt = 0; rt < 4; ++rt)
                    acc[rt][ct] = __builtin_amdgcn_mfma_f32_16x16x32_bf16(a[rt], bb, acc[rt][ct], 0, 0, 0);
            }
        }
        __syncthreads();
    }

    if (tid < 128){ statS[tid] = 0.f; statQ[tid] = 0.f; }
    __syncthreads();

    float cs[4] = {0,0,0,0}, cq[4] = {0,0,0,0};
    #pragma unroll
    for (int ct = 0; ct < 4; ++ct){
        int lcol = wvc*64 + ct*16 + mrow;
        int col  = cb0 + lcol;
        float bvv = bias[col];
        #pragma unroll
        for (int rt = 0; rt < 4; ++rt){
            #pragma unroll
            for (int reg = 0; reg < 4; ++reg){
                int row = row0 + wvr*64 + rt*16 + q*4 + reg;
                __bf16 ov = (__bf16)(acc[rt][ct][reg] + bvv);
                outp[(size_t)row*Ctot + col] = ov;
                float fv = (float)ov; cs[ct] += fv; cq[ct] += fv*fv;
            }
        }
    }
    #pragma unroll
    for (int ct = 0; ct < 4; ++ct){
        float s  = cs[ct]; s  += __shfl_xor(s, 16);  s  += __shfl_xor(s, 32);
        float qq = cq[ct]; qq += __shfl_xor(qq, 16); qq += __shfl_xor(qq, 32);
        if (q == 0){
            atomicAdd(&statS[wvc*64 + ct*16 + mrow], s);
            atomicAdd(&statQ[wvc*64 + ct*16 + mrow], qq);
        }
    }
    __syncthreads();
    if (tid < 128){
        atomicAdd(&outstats[cb0 + tid],        statS[tid]);
        atomicAdd(&outstats[outK + cb0 + tid], statQ[tid]);
    }
}

// ---------------------------------------------------------------------------
// out[m] = relu(bn2(t2[m,:])) . W3 + b3   (one wave per row, bf16 in, f32 out)
// ---------------------------------------------------------------------------
__global__ __launch_bounds__(256) void final_kernel(const __bf16* __restrict__ t2,
                                                    const float* __restrict__ st,
                                                    const float* __restrict__ g,
                                                    const float* __restrict__ bta,
                                                    const float* __restrict__ W3,
                                                    const float* __restrict__ b3,
                                                    float* __restrict__ outp){
    int gid = blockIdx.x*256 + threadIdx.x;
    int wid = gid >> 6, lane = gid & 63;
    int c0 = lane*4;
    bf16x4 v  = *(const bf16x4*)&t2[(size_t)wid*256 + c0];
    float4 w3 = *(const float4*)&W3[c0];
    float4 gg = *(const float4*)&g[c0];
    float4 bb = *(const float4*)&bta[c0];
    float4 sm = *(const float4*)&st[c0];
    float4 sq = *(const float4*)&st[256 + c0];
    float accv = 0.f;
    {
        float mean, var, val;
        mean = sm.x*(1.f/32768.f); var = sq.x*(1.f/32768.f) - mean*mean;
        val = ((float)v[0]-mean)*(gg.x/sqrtf(var+EPSBN)) + bb.x; accv += fmaxf(val,0.f)*w3.x;
        mean = sm.y*(1.f/32768.f); var = sq.y*(1.f/32768.f) - mean*mean;
        val = ((float)v[1]-mean)*(gg.y/sqrtf(var+EPSBN)) + bb.y; accv += fmaxf(val,0.f)*w3.y;
        mean = sm.z*(1.f/32768.f); var = sq.z*(1.f/32768.f) - mean*mean;
        val = ((float)v[2]-mean)*(gg.z/sqrtf(var+EPSBN)) + bb.z; accv += fmaxf(val,0.f)*w3.z;
        mean = sm.w*(1.f/32768.f); var = sq.w*(1.f/32768.f) - mean*mean;
        val = ((float)v[3]-mean)*(gg.w/sqrtf(var+EPSBN)) + bb.w; accv += fmaxf(val,0.f)*w3.w;
    }
    for (int off = 32; off; off >>= 1) accv += __shfl_down(accv, off);
    if (lane == 0) outp[wid] = accv + b3[0];
}

// ---------------------------------------------------------------------------
extern "C" void kernel_launch(void* const* d_in, const int* in_sizes, int n_in,
                              void* d_out, int out_size, void* d_ws, size_t ws_size,
                              hipStream_t stream)
{
    (void)in_sizes; (void)n_in; (void)out_size; (void)ws_size;
    const float* data   = (const float*)d_in[0];
    const float* emb    = (const float*)d_in[1];
    const float* lin_W  = (const float*)d_in[2];
    const float* att_i  = (const float*)d_in[3];
    const float* att_j  = (const float*)d_in[4];
    const float* aem_i  = (const float*)d_in[5];
    const float* aem_j  = (const float*)d_in[6];
    const float* gnn_bias = (const float*)d_in[7];
    const float* gnn_g  = (const float*)d_in[8];
    const float* gnn_b  = (const float*)d_in[9];
    const float* bno_g  = (const float*)d_in[10];
    const float* bno_b  = (const float*)d_in[11];
    const float* W1     = (const float*)d_in[12];
    const float* b1     = (const float*)d_in[13];
    const float* bn1_g  = (const float*)d_in[14];
    const float* bn1_b  = (const float*)d_in[15];
    const float* W2     = (const float*)d_in[16];
    const float* b2     = (const float*)d_in[17];
    const float* bn2_g  = (const float*)d_in[18];
    const float* bn2_b  = (const float*)d_in[19];
    const float* W3     = (const float*)d_in[20];
    const float* b3     = (const float*)d_in[21];
    float* outp = (float*)d_out;
    char*  ws   = (char*)d_ws;

    // workspace layout (bytes)
    int*    topk     = (int*)ws;                        // 64 KB
    float*  e_i      = (float*)(ws + 65536);
    float*  e_j      = (float*)(ws + 67584);
    float*  s_i      = (float*)(ws + 69632);            // 128 KB
    float*  s_j      = (float*)(ws + 200704);           // 128 KB
    float*  stats    = (float*)(ws + 331776);           // 1536 floats
    float*  gnnstats = stats;                           // [256]
    float*  hstats   = stats + 256;                     // [256]
    float*  bn1stats = stats + 512;                     // [512]
    float*  bn2stats = stats + 1024;                    // [512]
    __bf16* Wp1      = (__bf16*)(ws + 337920);          // 64 KB
    __bf16* Wp2      = (__bf16*)(ws + 403456);          // 128 KB
    __bf16* xlin     = (__bf16*)(ws + 1048576);                    // 8 MB
    __bf16* aggb     = (__bf16*)(ws + 1048576 +   8388608);        // 8 MB
    __bf16* t1       = (__bf16*)(ws + 1048576 + 2*8388608);        // 16 MB
    __bf16* t2       = (__bf16*)(ws + 1048576 + 2*8388608 + 16777216); // 16 MB

    // K1: xlin GEMM (+raw scores) || topk(bitonic)+e-scores || pack || zero
    k1_kernel<<<1073, 256, 0, stream>>>(data, emb, lin_W, W1, W2, att_i, att_j,
                                        aem_i, aem_j, topk, e_i, e_j,
                                        Wp1, Wp2, stats, xlin, s_i, s_j);

    // agg (one wave/node, XCD-local batches, NO fused stats)
    agg_kernel<<<8192, 256, 0, stream>>>(xlin, s_i, s_j, e_i, e_j, topk,
                                         (const float2*)gnn_bias, aggb);

    colstats_kernel<<<256, 256, 0, stream>>>(aggb, gnnstats);
    hstats_kernel<<<256, 256, 0, stream>>>(aggb, gnnstats, gnn_g, gnn_b, emb, hstats);

    // t1 = relu(bn_out( relu(bn_gnn(agg))*emb )) @ W1 + b1   (+ bn1 stats)
    gemm2_kernel<true><<<dim3(256,2), 256, 0, stream>>>(
        aggb, 128, 128, gnnstats, gnn_g, gnn_b, emb, hstats, bno_g, bno_b,
        Wp1, 256, b1, t1, bn1stats, 256);

    // t2 = relu(bn1(t1)) @ W2 + b2   (K=256, + bn2 stats)
    gemm2_kernel<false><<<dim3(256,2), 256, 0, stream>>>(
        t1, 256, 256, bn1stats, bn1_g, bn1_b, nullptr, nullptr, nullptr, nullptr,
        Wp2, 256, b2, t2, bn2stats, 256);

    final_kernel<<<M_ROWS/4, 256, 0, stream>>>(t2, bn2stats, bn2_g, bn2_b, W3, b3, outp);
}

// Round 9
// 240.506 us; speedup vs baseline: 1.7939x; 1.0253x over previous
//
#include <hip/hip_runtime.h>
#include <math.h>

// Problem constants (B=64, N=512, F_IN=D=128, K=32, INTER=256)
#define M_ROWS 32768
#define NNODES 512
#define KNBR   32
#define EPSBN  1e-5f

typedef __bf16 bf16x8 __attribute__((ext_vector_type(8)));
typedef __bf16 bf16x4 __attribute__((ext_vector_type(4)));
typedef __bf16 bf16x2 __attribute__((ext_vector_type(2)));
typedef float  f32x4  __attribute__((ext_vector_type(4)));

#if defined(__has_builtin)
#if __has_builtin(__builtin_amdgcn_global_load_lds)
#define HAVE_GLL 1
#endif
#endif

// async global->LDS 16B: LDS dst must be wave-uniform base + lane*16
__device__ __forceinline__ void async_ld16(void* lds, const void* g){
#ifdef HAVE_GLL
    __builtin_amdgcn_global_load_lds((__attribute__((address_space(1))) void*)(g),
                                     (__attribute__((address_space(3))) void*)(lds),
                                     16, 0, 0);
#else
    *(bf16x8*)lds = *(const bf16x8*)g;
#endif
}

// ---------------------------------------------------------------------------
// K1: blocks 0..511    -> xlin GEMM tile (64 rows) + raw score epilogue
//     blocks 512..1023 -> topk row (bitonic sort, all 256 thr) + e-scores
//     blocks 1024..1071-> pack W1/W2 to bf16 frag order
//     block  1072      -> zero BN stats + gnnpart slices
// ---------------------------------------------------------------------------
__global__ __launch_bounds__(256) void k1_kernel(
    const float* __restrict__ data, const float* __restrict__ emb,
    const float* __restrict__ lin_W, const float* __restrict__ W1,
    const float* __restrict__ W2,
    const float* __restrict__ att_i, const float* __restrict__ att_j,
    const float* __restrict__ aem_i, const float* __restrict__ aem_j,
    int* __restrict__ topk, float* __restrict__ e_i, float* __restrict__ e_j,
    __bf16* __restrict__ Wp1, __bf16* __restrict__ Wp2,
    float* __restrict__ stats, float* __restrict__ gnnpart,
    __bf16* __restrict__ xlin, float* __restrict__ s_i, float* __restrict__ s_j)
{
    __shared__ __align__(16) char sm[50176];   // union: xlin tiles / topk bufs
    int bid = blockIdx.x, tid = threadIdx.x;

    if (bid < 512){
        // ================= xlin GEMM tile =================
        __bf16 (*As)[136] = (__bf16(*)[136])sm;          // 64 x 136
        bf16x8* Bp = (bf16x8*)(sm + 17408);              // 2048 granules
        int lane = tid & 63, wv = tid >> 6;
        int mrow = lane & 15, q = lane >> 4;
        int row0 = bid * 64;

        // self-pack lin_W: Bp[g][j] = lin_W[((g>>7)*8 + j)*128 + (g&127)]
        #pragma unroll
        for (int i = 0; i < 8; ++i){
            int g = tid + i*256;
            int kg = g >> 7, c = g & 127;
            bf16x8 pk;
            #pragma unroll
            for (int j = 0; j < 8; ++j) pk[j] = (__bf16)lin_W[(size_t)(kg*8 + j)*128 + c];
            Bp[g] = pk;
        }
        // stage A fp32 -> bf16
        #pragma unroll
        for (int i = 0; i < 4; ++i){
            int p = tid + i*256;
            int r = p >> 4, c8 = p & 15;
            const float* src = &data[(size_t)(row0 + r)*128 + c8*8];
            float4 a0 = *(const float4*)src;
            float4 a1 = *(const float4*)(src + 4);
            bf16x8 o;
            o[0]=(__bf16)a0.x; o[1]=(__bf16)a0.y; o[2]=(__bf16)a0.z; o[3]=(__bf16)a0.w;
            o[4]=(__bf16)a1.x; o[5]=(__bf16)a1.y; o[6]=(__bf16)a1.z; o[7]=(__bf16)a1.w;
            *(bf16x8*)&As[r][c8*8] = o;
        }
        __syncthreads();

        f32x4 acc[8];
        #pragma unroll
        for (int ct = 0; ct < 8; ++ct) acc[ct] = (f32x4){0.f,0.f,0.f,0.f};
        #pragma unroll
        for (int ks = 0; ks < 4; ++ks){
            bf16x8 a = *(const bf16x8*)&As[wv*16 + mrow][ks*32 + q*8];
            #pragma unroll
            for (int ct = 0; ct < 8; ++ct){
                bf16x8 bb = Bp[(ks*4 + q)*128 + ct*16 + mrow];
                acc[ct] = __builtin_amdgcn_mfma_f32_16x16x32_bf16(a, bb, acc[ct], 0, 0, 0);
            }
        }

        // epilogue: store bf16 + raw attention scores (e_i/e_j added in agg)
        float ai[4] = {0,0,0,0}, aj[4] = {0,0,0,0};
        #pragma unroll
        for (int ct = 0; ct < 8; ++ct){
            int col = ct*16 + mrow;
            float wti = att_i[col], wtj = att_j[col];
            #pragma unroll
            for (int reg = 0; reg < 4; ++reg){
                int row = row0 + wv*16 + q*4 + reg;
                float v = acc[ct][reg];
                xlin[(size_t)row*128 + col] = (__bf16)v;
                ai[reg] += v*wti; aj[reg] += v*wtj;
            }
        }
        #pragma unroll
        for (int mask = 1; mask < 16; mask <<= 1){
            #pragma unroll
            for (int reg = 0; reg < 4; ++reg){
                ai[reg] += __shfl_xor(ai[reg], mask);
                aj[reg] += __shfl_xor(aj[reg], mask);
            }
        }
        if (mrow == 0){
            #pragma unroll
            for (int reg = 0; reg < 4; ++reg){
                int row = row0 + wv*16 + q*4 + reg;
                s_i[row] = ai[reg];
                s_j[row] = aj[reg];
            }
        }
        return;
    }

    if (bid >= 1024){
        if (bid == 1072){
            for (int i = tid; i < 1536; i += 256) stats[i] = 0.f;
            for (int i = tid; i < 16384; i += 256) gnnpart[i] = 0.f;
            return;
        }
        // pack W1 (4096 granules) then W2 (8192 granules)
        int gidx = (bid - 1024)*256 + tid;            // 0..12287
        const float* W; __bf16* o; int lg;
        if (gidx < 4096){ W = W1; o = Wp1; lg = gidx; }
        else            { W = W2; o = Wp2; lg = gidx - 4096; }
        int kg = lg >> 8, c = lg & 255;
        bf16x8 pk;
        #pragma unroll
        for (int j = 0; j < 8; ++j) pk[j] = (__bf16)W[(size_t)(kg*8 + j)*256 + c];
        *(bf16x8*)&o[(size_t)lg*8] = pk;
        return;
    }

    // ============ topk via bitonic sort (all 256 thr) + e-scores ==========
    float* wi   = (float*)sm;            // 128 floats
    float* sval = (float*)(sm + 512);    // 512 floats (cos values)
    int*   sidx = (int*)(sm + 2560);     // 512 ints
    int row = bid - 512;
    if (tid < 128) wi[tid] = emb[row*128 + tid];
    __syncthreads();

    // wave 1: e_i[row], e_j[row] (overlaps cos loop below)
    if (tid >= 64 && tid < 128){
        int lane = tid - 64;
        float ai = wi[lane]*aem_i[lane] + wi[lane+64]*aem_i[lane+64];
        float aj = wi[lane]*aem_j[lane] + wi[lane+64]*aem_j[lane+64];
        #pragma unroll
        for (int off = 32; off; off >>= 1){
            ai += __shfl_down(ai, off);
            aj += __shfl_down(aj, off);
        }
        if (lane == 0){ e_i[row] = ai; e_j[row] = aj; }
    }

    float ni = 0.f;
    #pragma unroll 8
    for (int d = 0; d < 128; ++d) ni += wi[d]*wi[d];
    float rni = sqrtf(ni);
    for (int jj = tid; jj < 512; jj += 256){
        const float4* wj4 = (const float4*)(emb + jj*128);
        float dot = 0.f, nj = 0.f;
        #pragma unroll 8
        for (int d4 = 0; d4 < 32; ++d4){
            float4 w = wj4[d4];
            dot += wi[4*d4+0]*w.x + wi[4*d4+1]*w.y + wi[4*d4+2]*w.z + wi[4*d4+3]*w.w;
            nj  += w.x*w.x + w.y*w.y + w.z*w.z + w.w*w.w;
        }
        sval[jj] = dot / (rni * sqrtf(nj));
        sidx[jj] = jj;
    }
    __syncthreads();

    // bitonic sort: strict order (value desc, index asc) == jax.lax.top_k
    #pragma unroll 1
    for (int k = 2; k <= 512; k <<= 1){
        #pragma unroll 1
        for (int j = k >> 1; j > 0; j >>= 1){
            int i2 = ((tid & ~(j-1)) << 1) | (tid & (j-1));
            int p  = i2 | j;
            float vi = sval[i2], vp = sval[p];
            int   xi = sidx[i2], xp = sidx[p];
            bool i_before_p = (vi > vp) || (vi == vp && xi < xp);
            bool up = ((i2 & k) == 0);
            if (up ? !i_before_p : i_before_p){
                sval[i2] = vp; sval[p] = vi;
                sidx[i2] = xp; sidx[p] = xi;
            }
            __syncthreads();
        }
    }
    if (tid < KNBR) topk[row*KNBR + tid] = sidx[tid];
}

// ---------------------------------------------------------------------------
// agg v5: ONE WAVE per node (8192 blocks x 4 waves), XCD-locality swizzle,
// shuffle softmax, fully-unrolled gather with upfront broadcasts (ILP),
// fused gnn column stats into 64 SLICED partial buffers (128 RMWs/address).
// ---------------------------------------------------------------------------
__global__ __launch_bounds__(256) void agg_kernel(const __bf16* __restrict__ xl,
                                                  const float* __restrict__ s_i,
                                                  const float* __restrict__ s_j,
                                                  const float* __restrict__ e_i,
                                                  const float* __restrict__ e_j,
                                                  const int* __restrict__ topk,
                                                  const float2* __restrict__ gnn_bias2,
                                                  __bf16* __restrict__ aggp,
                                                  float* __restrict__ gnnpart){
    int tid = threadIdx.x;
    int wv = tid >> 6, lane = tid & 63;
    int blk = blockIdx.x;                        // 0..8191
    int xcd = blk & 7, grp = blk >> 3;           // grp 0..1023
    int batch = xcd*8 + (grp >> 7);              // 0..63
    int node  = (grp & 127)*4 + wv;              // 0..511
    int m = batch*512 + node;
    int i = node;

    int src; bool valid;
    if (lane < KNBR){ int j = topk[i*KNBR + lane]; src = batch*512 + j; valid = (j != i); }
    else            { src = m; valid = (lane == KNBR); }
    float l = s_i[m] + e_i[i] + s_j[src] + e_j[src & 511];
    l = (l >= 0.f) ? l : 0.2f*l;                 // leaky_relu 0.2
    l = valid ? l : -1e30f;
    float mx = l;
    #pragma unroll
    for (int mask = 1; mask < 64; mask <<= 1) mx = fmaxf(mx, __shfl_xor(mx, mask));
    float e = valid ? __expf(l - mx) : 0.f;
    float den = e;
    #pragma unroll
    for (int mask = 1; mask < 64; mask <<= 1) den += __shfl_xor(den, mask);
    float alpha = e / den;

    // broadcast all 33 (alpha, src) upfront, then fully-unrolled gathers
    float ak[33]; int sk[33];
    #pragma unroll
    for (int k = 0; k < 33; ++k){
        ak[k] = __shfl(alpha, k);
        sk[k] = __shfl(src, k);
    }
    float ax0 = 0.f, ay0 = 0.f, ax1 = 0.f, ay1 = 0.f;
    #pragma unroll
    for (int k = 0; k < 33; ++k){
        bf16x2 v = *(const bf16x2*)&xl[(size_t)sk[k]*128 + lane*2];
        if (k & 1){ ax1 += ak[k]*(float)v[0]; ay1 += ak[k]*(float)v[1]; }
        else      { ax0 += ak[k]*(float)v[0]; ay0 += ak[k]*(float)v[1]; }
    }
    float2 bv = gnn_bias2[lane];
    bf16x2 o;
    o[0] = (__bf16)(ax0 + ax1 + bv.x);
    o[1] = (__bf16)(ay0 + ay1 + bv.y);
    *(bf16x2*)&aggp[(size_t)m*128 + lane*2] = o;

    // sliced gnn column stats (on rounded values): slice = blk & 63
    float r0 = (float)o[0], r1 = (float)o[1];
    __shared__ float rS[4][128], rQ[4][128];
    rS[wv][lane*2]   = r0;    rS[wv][lane*2+1] = r1;
    rQ[wv][lane*2]   = r0*r0; rQ[wv][lane*2+1] = r1*r1;
    __syncthreads();
    if (tid < 128){
        float ts = rS[0][tid] + rS[1][tid] + rS[2][tid] + rS[3][tid];
        float tq = rQ[0][tid] + rQ[1][tid] + rQ[2][tid] + rQ[3][tid];
        float* slice = gnnpart + (blk & 63)*256;
        atomicAdd(&slice[tid],       ts);
        atomicAdd(&slice[128 + tid], tq);
    }
}

// ---------------------------------------------------------------------------
// hstats: prologue reduces the 64 gnnpart slices -> gnn stats (block 0 also
// publishes gnnstats for the GATE GEMM); then h = relu(bn_gnn(agg))*emb on
// the fly (NOT stored) and column sum/sumsq of h into hstats.
// ---------------------------------------------------------------------------
__global__ __launch_bounds__(256) void hstats_kernel(const __bf16* __restrict__ agg,
                                                     const float* __restrict__ gnnpart,
                                                     float* __restrict__ gnnstats,
                                                     const float* __restrict__ g,
                                                     const float* __restrict__ bta,
                                                     const float* __restrict__ emb,
                                                     float* __restrict__ hstats){
    __shared__ float gred[256];
    int tid = threadIdx.x;
    {   // reduce 64 slices for stat component `tid` (0..127 sum, 128..255 sumsq)
        float t = 0.f;
        #pragma unroll 8
        for (int s2 = 0; s2 < 64; ++s2) t += gnnpart[s2*256 + tid];
        gred[tid] = t;
        if (blockIdx.x == 0) gnnstats[tid] = t;   // publish for GATE GEMM
    }
    __syncthreads();

    int cg = tid & 31, rs = tid >> 5;
    int c0 = cg*4;
    float sc[4], sh[4];
    #pragma unroll
    for (int j = 0; j < 4; ++j){
        float mean = gred[c0+j] * (1.f/32768.f);
        float var  = gred[128 + c0+j] * (1.f/32768.f) - mean*mean;
        sc[j] = g[c0+j] / sqrtf(var + EPSBN);
        sh[j] = bta[c0+j] - mean*sc[j];
    }
    float s[4] = {0,0,0,0}, qq[4] = {0,0,0,0};
    for (int m = blockIdx.x*8 + rs; m < M_ROWS; m += gridDim.x*8){
        bf16x4 v = *(const bf16x4*)&agg[(size_t)m*128 + c0];
        float4 e = *(const float4*)&emb[(size_t)(m & 511)*128 + c0];
        float f0 = fmaxf((float)v[0]*sc[0] + sh[0], 0.f) * e.x;
        float f1 = fmaxf((float)v[1]*sc[1] + sh[1], 0.f) * e.y;
        float f2 = fmaxf((float)v[2]*sc[2] + sh[2], 0.f) * e.z;
        float f3 = fmaxf((float)v[3]*sc[3] + sh[3], 0.f) * e.w;
        s[0]+=f0; qq[0]+=f0*f0; s[1]+=f1; qq[1]+=f1*f1;
        s[2]+=f2; qq[2]+=f2*f2; s[3]+=f3; qq[3]+=f3*f3;
    }
    __shared__ float rS[8][128], rQ[8][128];
    #pragma unroll
    for (int j = 0; j < 4; ++j){ rS[rs][c0+j] = s[j]; rQ[rs][c0+j] = qq[j]; }
    __syncthreads();
    if (tid < 128){
        float ts = 0.f, tq = 0.f;
        #pragma unroll
        for (int u = 0; u < 8; ++u){ ts += rS[u][tid]; tq += rQ[u][tid]; }
        atomicAdd(&hstats[tid],       ts);
        atomicAdd(&hstats[128 + tid], tq);
    }
}

// ---------------------------------------------------------------------------
// bf16 MFMA GEMM (128x128 tile, 2x2 wave grid).
// GATE: A-staging = relu(bn_out( relu(bn_gnn(agg)) * emb )), K=128
// else: A-staging = relu(bn1(t1)), K=256
// ---------------------------------------------------------------------------
template<bool GATE>
__global__ __launch_bounds__(256) void gemm2_kernel(
    const __bf16* __restrict__ A, int a_stride, int Ktot,
    const float* __restrict__ st1, const float* __restrict__ g1, const float* __restrict__ b1,
    const float* __restrict__ emb,
    const float* __restrict__ st2, const float* __restrict__ g2, const float* __restrict__ b2,
    const __bf16* __restrict__ Wp, int Ctot,
    const float* __restrict__ bias,
    __bf16* __restrict__ outp,
    float* __restrict__ outstats, int outK)
{
    __shared__ __align__(16) __bf16 As[128][136];
    __shared__ __align__(16) __bf16 Bp[16][128][8];
    __shared__ float nsc1[128], nsh1[128], nsc2[128], nsh2[128];
    __shared__ float statS[128], statQ[128];

    int tid  = threadIdx.x;
    int lane = tid & 63, wv = tid >> 6;
    int mrow = lane & 15, q = lane >> 4;
    int wvr = wv & 1, wvc = wv >> 1;             // 2x2 wave grid
    int cb0  = blockIdx.y * 128;
    int row0 = blockIdx.x * 128;

    f32x4 acc[4][4];
    #pragma unroll
    for (int rt = 0; rt < 4; ++rt)
        #pragma unroll
        for (int ct = 0; ct < 4; ++ct)
            acc[rt][ct] = (f32x4){0.f,0.f,0.f,0.f};

    for (int kc = 0; kc < Ktot; kc += 128){
        if (tid < 128){
            int f = kc + tid;
            float mean = st1[f] * (1.f/32768.f);
            float var  = st1[Ktot + f] * (1.f/32768.f) - mean*mean;
            float sc   = g1[f] / sqrtf(var + EPSBN);
            nsc1[tid] = sc;
            nsh1[tid] = b1[f] - mean*sc;
            if (GATE){
                float mean2 = st2[tid] * (1.f/32768.f);
                float var2  = st2[128 + tid] * (1.f/32768.f) - mean2*mean2;
                float sc2   = g2[tid] / sqrtf(var2 + EPSBN);
                nsc2[tid] = sc2;
                nsh2[tid] = b2[tid] - mean2*sc2;
            }
        }
        __syncthreads();

        // B: async 16B granules into LDS (pre-packed frag order)
        int kg0 = kc >> 3;
        #pragma unroll
        for (int i = 0; i < 8; ++i){
            int p = tid + i*256;
            const __bf16* src = Wp + ((size_t)(kg0 + (p>>7))*Ctot + cb0 + (p&127))*8;
            async_ld16((__bf16*)Bp + (size_t)p*8, src);
        }
        // A: through regs with fused activation chain
        #pragma unroll
        for (int i = 0; i < 8; ++i){
            int p = tid + i*256;
            int r = p >> 4, c8 = p & 15;
            bf16x8 v = *(const bf16x8*)&A[(size_t)(row0 + r)*a_stride + kc + c8*8];
            bf16x8 o;
            if (GATE){
                const float* ep = &emb[(size_t)((row0 + r) & 511)*128 + c8*8];
                float4 e0 = *(const float4*)ep;
                float4 e1 = *(const float4*)(ep + 4);
                float ee[8] = {e0.x,e0.y,e0.z,e0.w,e1.x,e1.y,e1.z,e1.w};
                #pragma unroll
                for (int j = 0; j < 8; ++j){
                    int f = c8*8 + j;
                    float hv = fmaxf((float)v[j]*nsc1[f] + nsh1[f], 0.f) * ee[j];
                    o[j] = (__bf16)fmaxf(hv*nsc2[f] + nsh2[f], 0.f);
                }
            } else {
                #pragma unroll
                for (int j = 0; j < 8; ++j){
                    int f = c8*8 + j;
                    o[j] = (__bf16)fmaxf((float)v[j]*nsc1[f] + nsh1[f], 0.f);
                }
            }
            *(bf16x8*)&As[r][c8*8] = o;
        }
        __syncthreads();

        #pragma unroll
        for (int ks = 0; ks < 4; ++ks){
            bf16x8 a[4];
            #pragma unroll
            for (int rt = 0; rt < 4; ++rt)
                a[rt] = *(const bf16x8*)&As[wvr*64 + rt*16 + mrow][ks*32 + q*8];
            #pragma unroll
            for (int ct = 0; ct < 4; ++ct){
                bf16x8 bb = *(const bf16x8*)&Bp[ks*4 + q][wvc*64 + ct*16 + mrow][0];
                #pragma unroll
                for (int rt = 0; rt < 4; ++rt)
                    acc[rt][ct] = __builtin_amdgcn_mfma_f32_16x16x32_bf16(a[rt], bb, acc[rt][ct], 0, 0, 0);
            }
        }
        __syncthreads();
    }

    if (tid < 128){ statS[tid] = 0.f; statQ[tid] = 0.f; }
    __syncthreads();

    float cs[4] = {0,0,0,0}, cq[4] = {0,0,0,0};
    #pragma unroll
    for (int ct = 0; ct < 4; ++ct){
        int lcol = wvc*64 + ct*16 + mrow;
        int col  = cb0 + lcol;
        float bvv = bias[col];
        #pragma unroll
        for (int rt = 0; rt < 4; ++rt){
            #pragma unroll
            for (int reg = 0; reg < 4; ++reg){
                int row = row0 + wvr*64 + rt*16 + q*4 + reg;
                __bf16 ov = (__bf16)(acc[rt][ct][reg] + bvv);
                outp[(size_t)row*Ctot + col] = ov;
                float fv = (float)ov; cs[ct] += fv; cq[ct] += fv*fv;
            }
        }
    }
    #pragma unroll
    for (int ct = 0; ct < 4; ++ct){
        float s  = cs[ct]; s  += __shfl_xor(s, 16);  s  += __shfl_xor(s, 32);
        float qq = cq[ct]; qq += __shfl_xor(qq, 16); qq += __shfl_xor(qq, 32);
        if (q == 0){
            atomicAdd(&statS[wvc*64 + ct*16 + mrow], s);
            atomicAdd(&statQ[wvc*64 + ct*16 + mrow], qq);
        }
    }
    __syncthreads();
    if (tid < 128){
        atomicAdd(&outstats[cb0 + tid],        statS[tid]);
        atomicAdd(&outstats[outK + cb0 + tid], statQ[tid]);
    }
}

// ---------------------------------------------------------------------------
// out[m] = relu(bn2(t2[m,:])) . W3 + b3   (one wave per row, bf16 in, f32 out)
// ---------------------------------------------------------------------------
__global__ __launch_bounds__(256) void final_kernel(const __bf16* __restrict__ t2,
                                                    const float* __restrict__ st,
                                                    const float* __restrict__ g,
                                                    const float* __restrict__ bta,
                                                    const float* __restrict__ W3,
                                                    const float* __restrict__ b3,
                                                    float* __restrict__ outp){
    int gid = blockIdx.x*256 + threadIdx.x;
    int wid = gid >> 6, lane = gid & 63;
    int c0 = lane*4;
    bf16x4 v  = *(const bf16x4*)&t2[(size_t)wid*256 + c0];
    float4 w3 = *(const float4*)&W3[c0];
    float4 gg = *(const float4*)&g[c0];
    float4 bb = *(const float4*)&bta[c0];
    float4 sm = *(const float4*)&st[c0];
    float4 sq = *(const float4*)&st[256 + c0];
    float accv = 0.f;
    {
        float mean, var, val;
        mean = sm.x*(1.f/32768.f); var = sq.x*(1.f/32768.f) - mean*mean;
        val = ((float)v[0]-mean)*(gg.x/sqrtf(var+EPSBN)) + bb.x; accv += fmaxf(val,0.f)*w3.x;
        mean = sm.y*(1.f/32768.f); var = sq.y*(1.f/32768.f) - mean*mean;
        val = ((float)v[1]-mean)*(gg.y/sqrtf(var+EPSBN)) + bb.y; accv += fmaxf(val,0.f)*w3.y;
        mean = sm.z*(1.f/32768.f); var = sq.z*(1.f/32768.f) - mean*mean;
        val = ((float)v[2]-mean)*(gg.z/sqrtf(var+EPSBN)) + bb.z; accv += fmaxf(val,0.f)*w3.z;
        mean = sm.w*(1.f/32768.f); var = sq.w*(1.f/32768.f) - mean*mean;
        val = ((float)v[3]-mean)*(gg.w/sqrtf(var+EPSBN)) + bb.w; accv += fmaxf(val,0.f)*w3.w;
    }
    for (int off = 32; off; off >>= 1) accv += __shfl_down(accv, off);
    if (lane == 0) outp[wid] = accv + b3[0];
}

// ---------------------------------------------------------------------------
extern "C" void kernel_launch(void* const* d_in, const int* in_sizes, int n_in,
                              void* d_out, int out_size, void* d_ws, size_t ws_size,
                              hipStream_t stream)
{
    (void)in_sizes; (void)n_in; (void)out_size; (void)ws_size;
    const float* data   = (const float*)d_in[0];
    const float* emb    = (const float*)d_in[1];
    const float* lin_W  = (const float*)d_in[2];
    const float* att_i  = (const float*)d_in[3];
    const float* att_j  = (const float*)d_in[4];
    const float* aem_i  = (const float*)d_in[5];
    const float* aem_j  = (const float*)d_in[6];
    const float* gnn_bias = (const float*)d_in[7];
    const float* gnn_g  = (const float*)d_in[8];
    const float* gnn_b  = (const float*)d_in[9];
    const float* bno_g  = (const float*)d_in[10];
    const float* bno_b  = (const float*)d_in[11];
    const float* W1     = (const float*)d_in[12];
    const float* b1     = (const float*)d_in[13];
    const float* bn1_g  = (const float*)d_in[14];
    const float* bn1_b  = (const float*)d_in[15];
    const float* W2     = (const float*)d_in[16];
    const float* b2     = (const float*)d_in[17];
    const float* bn2_g  = (const float*)d_in[18];
    const float* bn2_b  = (const float*)d_in[19];
    const float* W3     = (const float*)d_in[20];
    const float* b3     = (const float*)d_in[21];
    float* outp = (float*)d_out;
    char*  ws   = (char*)d_ws;

    // workspace layout (bytes)
    int*    topk     = (int*)ws;                        // 64 KB
    float*  e_i      = (float*)(ws + 65536);
    float*  e_j      = (float*)(ws + 67584);
    float*  s_i      = (float*)(ws + 69632);            // 128 KB
    float*  s_j      = (float*)(ws + 200704);           // 128 KB
    float*  stats    = (float*)(ws + 331776);           // 1536 floats
    float*  gnnstats = stats;                           // [256]
    float*  hstats   = stats + 256;                     // [256]
    float*  bn1stats = stats + 512;                     // [512]
    float*  bn2stats = stats + 1024;                    // [512]
    __bf16* Wp1      = (__bf16*)(ws + 337920);          // 64 KB
    __bf16* Wp2      = (__bf16*)(ws + 403456);          // 128 KB
    float*  gnnpart  = (float*)(ws + 534528);           // 64 slices x 256 = 64 KB
    __bf16* xlin     = (__bf16*)(ws + 1048576);                    // 8 MB
    __bf16* aggb     = (__bf16*)(ws + 1048576 +   8388608);        // 8 MB
    __bf16* t1       = (__bf16*)(ws + 1048576 + 2*8388608);        // 16 MB
    __bf16* t2       = (__bf16*)(ws + 1048576 + 2*8388608 + 16777216); // 16 MB

    // K1: xlin GEMM (+raw scores) || topk(bitonic)+e-scores || pack || zero
    k1_kernel<<<1073, 256, 0, stream>>>(data, emb, lin_W, W1, W2, att_i, att_j,
                                        aem_i, aem_j, topk, e_i, e_j,
                                        Wp1, Wp2, stats, gnnpart, xlin, s_i, s_j);

    // agg (one wave/node, XCD-local batches, sliced gnn stats fusion)
    agg_kernel<<<8192, 256, 0, stream>>>(xlin, s_i, s_j, e_i, e_j, topk,
                                         (const float2*)gnn_bias, aggb, gnnpart);

    // hstats (reduces gnnpart inline; block 0 publishes gnnstats)
    hstats_kernel<<<256, 256, 0, stream>>>(aggb, gnnpart, gnnstats,
                                           gnn_g, gnn_b, emb, hstats);

    // t1 = relu(bn_out( relu(bn_gnn(agg))*emb )) @ W1 + b1   (+ bn1 stats)
    gemm2_kernel<true><<<dim3(256,2), 256, 0, stream>>>(
        aggb, 128, 128, gnnstats, gnn_g, gnn_b, emb, hstats, bno_g, bno_b,
        Wp1, 256, b1, t1, bn1stats, 256);

    // t2 = relu(bn1(t1)) @ W2 + b2   (K=256, + bn2 stats)
    gemm2_kernel<false><<<dim3(256,2), 256, 0, stream>>>(
        t1, 256, 256, bn1stats, bn1_g, bn1_b, nullptr, nullptr, nullptr, nullptr,
        Wp2, 256, b2, t2, bn2stats, 256);

    final_kernel<<<M_ROWS/4, 256, 0, stream>>>(t2, bn2stats, bn2_g, bn2_b, W3, b3, outp);
}